// Round 3
// baseline (4232.228 us; speedup 1.0000x reference)
//
#include <hip/hip_runtime.h>

typedef unsigned int u32;
typedef unsigned short u16;
typedef __attribute__((ext_vector_type(8))) __bf16 bf16x8;
typedef __attribute__((ext_vector_type(4))) float f32x4;
typedef __attribute__((ext_vector_type(4))) u16 u16x4;

#define L_ 128
#define N_ 512
#define M_ 256
#define TK_ 4
#define H_ 8
#define R_ (L_*N_)
#define FF_ 1024

__device__ __forceinline__ u16 f2bf(float f){
  u32 u = __builtin_bit_cast(u32, f);
  u = (u + 0x7FFFu + ((u>>16)&1u)) >> 16;
  return (u16)u;
}
__device__ __forceinline__ float bf2f(u16 h){ u32 u=((u32)h)<<16; return __builtin_bit_cast(float,u); }
__device__ __forceinline__ f32x4 mfma16(bf16x8 a, bf16x8 b, f32x4 c){
  return __builtin_amdgcn_mfma_f32_16x16x32_bf16(a,b,c,0,0,0);
}
// acc += (ah+al)*(bh+bl), dropping al*bl (~2^-18)
__device__ __forceinline__ f32x4 mfma3(bf16x8 ah, bf16x8 al, bf16x8 bh, bf16x8 bl, f32x4 c){
  c = mfma16(ah, bh, c);
  c = mfma16(al, bh, c);
  c = mfma16(ah, bl, c);
  return c;
}
__device__ __forceinline__ void split4_store(float4 v, u16* hiP, u16* loP){
  u16 h0 = f2bf(v.x), h1 = f2bf(v.y), h2 = f2bf(v.z), h3 = f2bf(v.w);
  u16 l0 = f2bf(v.x - bf2f(h0));
  u16 l1 = f2bf(v.y - bf2f(h1));
  u16 l2 = f2bf(v.z - bf2f(h2));
  u16 l3 = f2bf(v.w - bf2f(h3));
  u16x4 hv, lv;
  hv[0]=h0; hv[1]=h1; hv[2]=h2; hv[3]=h3;
  lv[0]=l0; lv[1]=l1; lv[2]=l2; lv[3]=l3;
  *(u16x4*)hiP = hv;
  *(u16x4*)loP = lv;
}

// ---------------- prep ----------------
__global__ void k_bias(float* __restrict__ bias){
  int j = blockIdx.x, l = threadIdx.x;
  int t = l>>1;
  float base = expf(-0.14391156831212757f * (float)t); // ln(10000)/64
  float ang = (float)j * base;
  bias[j*M_ + l] = (l&1) ? cosf(ang) : sinf(ang);
}

// Wqkv[a,x,h,d,m] -> wqkvr[a][h*96 + x*32 + d][m]   (f32)
__global__ void k_prep_qkvw2(const float* __restrict__ w, float* __restrict__ dst){
  int b = blockIdx.x, m = threadIdx.x;
  int a = b/768, colp = b%768;
  int h = colp/96, rem = colp%96, x = rem/32, d = rem&31;
  dst[b*M_ + m] = w[(((a*3 + x)*H_ + h)*32 + d)*M_ + m];
}

// ---------------- k_init: out = x @ weight^T + bias ----------------
__global__ __launch_bounds__(512) void k_init(const float* __restrict__ X, const float* __restrict__ W,
    const float* __restrict__ bias, float* __restrict__ out){
  __shared__ __align__(16) u16 Ah[32*40], Al[32*40];
  __shared__ __align__(16) u16 Bh[256*40], Bl[256*40];
  int tid = threadIdx.x;
  int wid = tid>>6, lane = tid&63;
  int wr = wid>>2, wc = wid&3;
  int g = lane>>4, lr = lane&15;
  int rowbase = blockIdx.x*32;
  f32x4 zero = 0.f;
  f32x4 acc[4] = {zero,zero,zero,zero};
  for (int k0=0;k0<M_;k0+=32){
    if (tid < 256){
      int row = tid>>3, q = tid&7;
      float4 v = *(const float4*)(X + (rowbase+row)*M_ + k0 + q*4);
      split4_store(v, Ah + row*40 + q*4, Al + row*40 + q*4);
    }
    #pragma unroll
    for (int it=0; it<4; it++){
      int idx = tid + it*512;
      int row = idx>>3, q = idx&7;
      float4 v = *(const float4*)(W + row*M_ + k0 + q*4);
      split4_store(v, Bh + row*40 + q*4, Bl + row*40 + q*4);
    }
    __syncthreads();
    bf16x8 ah = *(const bf16x8*)(Ah + (wr*16 + lr)*40 + g*8);
    bf16x8 al = *(const bf16x8*)(Al + (wr*16 + lr)*40 + g*8);
    #pragma unroll
    for (int j=0;j<4;j++){
      int brow = wc*64 + j*16 + lr;
      bf16x8 bh = *(const bf16x8*)(Bh + brow*40 + g*8);
      bf16x8 bl = *(const bf16x8*)(Bl + brow*40 + g*8);
      acc[j] = mfma3(ah, al, bh, bl, acc[j]);
    }
    __syncthreads();
  }
  #pragma unroll
  for (int j=0;j<4;j++){
    #pragma unroll
    for (int r=0;r<4;r++){
      int row = rowbase + wr*16 + g*4 + r;
      int col = wc*64 + j*16 + lr;
      out[row*M_ + col] = acc[j][r] + bias[(row & (N_-1))*M_ + col];
    }
  }
}

// ---------------- LN(s) -> f32 ----------------
__global__ __launch_bounds__(256) void k_ln(const float* __restrict__ s, const float* __restrict__ lg,
    const float* __restrict__ lb, float* __restrict__ A){
  int tid = threadIdx.x;
  int rl = tid>>4, c16 = tid&15;
  int row = blockIdx.x*16 + rl;
  const float* sr = s + row*M_ + c16*16;
  float v[16];
  #pragma unroll
  for (int q=0;q<4;q++){
    float4 t = ((const float4*)sr)[q];
    v[q*4+0]=t.x; v[q*4+1]=t.y; v[q*4+2]=t.z; v[q*4+3]=t.w;
  }
  float sum=0.f, sq=0.f;
  #pragma unroll
  for (int e=0;e<16;e++){ sum+=v[e]; sq+=v[e]*v[e]; }
  #pragma unroll
  for (int o=1;o<16;o<<=1){ sum += __shfl_xor(sum,o); sq += __shfl_xor(sq,o); }
  float mean = sum*(1.f/M_);
  float var  = sq*(1.f/M_) - mean*mean;
  float rstd = rsqrtf(var + 1e-5f);
  float4* dst = (float4*)(A + row*M_ + c16*16);
  #pragma unroll
  for (int q=0;q<4;q++){
    int col = c16*16 + q*4;
    float4 o;
    o.x = (v[q*4+0]-mean)*rstd*lg[col+0] + lb[col+0];
    o.y = (v[q*4+1]-mean)*rstd*lg[col+1] + lb[col+1];
    o.z = (v[q*4+2]-mean)*rstd*lg[col+2] + lb[col+2];
    o.w = (v[q*4+3]-mean)*rstd*lg[col+3] + lb[col+3];
    dst[q] = o;
  }
}

// ---------------- QKV GEMM (split) + fused rsa -> imv(bf16, pre-scan) ----------------
// grid (R/32, 2); wave w: hg=w>>1 (head within 4-head group), sub=w&1 (row half)
__global__ __launch_bounds__(512) void k_qkv(const float* __restrict__ A, const float* __restrict__ Wq,
    u16* __restrict__ imv){
  __shared__ __align__(16) u16 Ah[32*40], Al[32*40];
  __shared__ __align__(16) u16 Bh[384*40], Bl[384*40];
  int tid = threadIdx.x;
  int wid = tid>>6, lane = tid&63;
  int hg = wid>>1, sub = wid&1;
  int g = lane>>4, lr = lane&15;
  int head = blockIdx.y*4 + hg;
  int rowbase = blockIdx.x*32;
  f32x4 zero = 0.f;
  f32x4 acc[6] = {zero,zero,zero,zero,zero,zero};
  for (int k0=0;k0<M_;k0+=32){
    if (tid < 256){
      int row = tid>>3, q = tid&7;
      float4 v = *(const float4*)(A + (rowbase+row)*M_ + k0 + q*4);
      split4_store(v, Ah + row*40 + q*4, Al + row*40 + q*4);
    }
    #pragma unroll
    for (int it=0; it<6; it++){
      int idx = tid + it*512;
      int row = idx>>3, q = idx&7;
      float4 v = *(const float4*)(Wq + (blockIdx.y*384 + row)*M_ + k0 + q*4);
      split4_store(v, Bh + row*40 + q*4, Bl + row*40 + q*4);
    }
    __syncthreads();
    bf16x8 ah = *(const bf16x8*)(Ah + (sub*16 + lr)*40 + g*8);
    bf16x8 al = *(const bf16x8*)(Al + (sub*16 + lr)*40 + g*8);
    #pragma unroll
    for (int c=0;c<6;c++){
      int brow = hg*96 + c*16 + lr;
      bf16x8 bh = *(const bf16x8*)(Bh + brow*40 + g*8);
      bf16x8 bl = *(const bf16x8*)(Bl + brow*40 + g*8);
      acc[c] = mfma3(ah, al, bh, bl, acc[c]);
    }
    __syncthreads();
  }
  const float isd = 0.17677669529663687f; // 1/sqrt(32)
  f32x4 p = acc[0]*acc[2] + acc[1]*acc[3];
  #pragma unroll
  for (int r=0;r<4;r++){
    float v = p[r];
    v += __shfl_xor(v,1); v += __shfl_xor(v,2);
    v += __shfl_xor(v,4); v += __shfl_xor(v,8);
    float rsa = v * isd;
    int row = rowbase + sub*16 + g*4 + r;
    #pragma unroll
    for (int c2=0;c2<2;c2++){
      imv[row*M_ + head*32 + c2*16 + lr] = f2bf(rsa*acc[4+c2][r]);
    }
  }
}

// ---------------- cumsum over j: imv(bf16) -> P1(f32) ----------------
__global__ void k_scan(const u16* __restrict__ imv, float* __restrict__ outp){
  int i = blockIdx.x, m = threadIdx.x;
  int base = i*N_*M_ + m;
  float acc = 0.f;
  for (int jb=0; jb<N_; jb+=8){
    float t[8];
    #pragma unroll
    for (int u=0;u<8;u++) t[u] = bf2f(imv[base + (jb+u)*M_]);
    #pragma unroll
    for (int u=0;u<8;u++){ acc += t[u]; outp[base + (jb+u)*M_] = acc; }
  }
}

// ---------------- Wo GEMM (split) + s_old + LN + residual -> smid f32 (in-place into P1) ----------------
__global__ __launch_bounds__(512) void k_wo(float* __restrict__ P1, const float* __restrict__ W,
    const float* __restrict__ sold, const float* __restrict__ lg, const float* __restrict__ lb){
  __shared__ __align__(16) u16 Ah[32*264], Al[32*264];
  __shared__ __align__(16) u16 Bh[256*40], Bl[256*40];
  __shared__ float zs[32][257];
  int tid = threadIdx.x;
  int wid = tid>>6, lane = tid&63;
  int wr = wid>>2, wc = wid&3;
  int g = lane>>4, lr = lane&15;
  int rowbase = blockIdx.x*32;
  // stage ALL of A (cumsum rows) upfront -> allows in-place smid write at end
  #pragma unroll
  for (int it=0; it<4; it++){
    int idx = tid + it*512;
    int row = idx>>6, q = idx&63;
    float4 v = *(const float4*)(P1 + (rowbase+row)*M_ + q*4);
    split4_store(v, Ah + row*264 + q*4, Al + row*264 + q*4);
  }
  f32x4 zero = 0.f;
  f32x4 acc[4] = {zero,zero,zero,zero};
  for (int k0=0;k0<M_;k0+=32){
    #pragma unroll
    for (int it=0; it<4; it++){
      int idx = tid + it*512;
      int row = idx>>3, q = idx&7;
      float4 v = *(const float4*)(W + row*M_ + k0 + q*4);
      split4_store(v, Bh + row*40 + q*4, Bl + row*40 + q*4);
    }
    __syncthreads();
    bf16x8 ah = *(const bf16x8*)(Ah + (wr*16 + lr)*264 + k0 + g*8);
    bf16x8 al = *(const bf16x8*)(Al + (wr*16 + lr)*264 + k0 + g*8);
    #pragma unroll
    for (int j=0;j<4;j++){
      int brow = wc*64 + j*16 + lr;
      bf16x8 bh = *(const bf16x8*)(Bh + brow*40 + g*8);
      bf16x8 bl = *(const bf16x8*)(Bl + brow*40 + g*8);
      acc[j] = mfma3(ah, al, bh, bl, acc[j]);
    }
    __syncthreads();
  }
  #pragma unroll
  for (int j=0;j<4;j++){
    #pragma unroll
    for (int r=0;r<4;r++){
      int rl = wr*16 + g*4 + r;
      int col = wc*64 + j*16 + lr;
      zs[rl][col] = acc[j][r] + sold[(rowbase+rl)*M_ + col];
    }
  }
  __syncthreads();
  int rl2 = tid>>4, c16 = tid&15;
  float sum=0.f, sq=0.f;
  float v[16];
  #pragma unroll
  for (int e=0;e<16;e++){ v[e] = zs[rl2][c16*16+e]; sum+=v[e]; sq+=v[e]*v[e]; }
  #pragma unroll
  for (int o=1;o<16;o<<=1){ sum += __shfl_xor(sum,o); sq += __shfl_xor(sq,o); }
  float mean = sum*(1.f/M_);
  float var  = sq*(1.f/M_) - mean*mean;
  float rstd = rsqrtf(var + 1e-5f);
  float4* dst = (float4*)(P1 + (rowbase+rl2)*M_ + c16*16);
  #pragma unroll
  for (int q=0;q<4;q++){
    int col = c16*16 + q*4;
    float4 o;
    o.x = (v[q*4+0]-mean)*rstd*lg[col+0] + lb[col+0] + v[q*4+0];
    o.y = (v[q*4+1]-mean)*rstd*lg[col+1] + lb[col+1] + v[q*4+1];
    o.z = (v[q*4+2]-mean)*rstd*lg[col+2] + lb[col+2] + v[q*4+2];
    o.w = (v[q*4+3]-mean)*rstd*lg[col+3] + lb[col+3] + v[q*4+3];
    dst[q] = o;
  }
}

// ---------------- fused MLP (split): gelu(smid@fc1^T+b1)@fc2^T + b2 -> out ----------------
__global__ __launch_bounds__(512) void k_fc(const float* __restrict__ A, const float* __restrict__ W1,
    const float* __restrict__ b1, const float* __restrict__ W2, const float* __restrict__ b2,
    float* __restrict__ out){
  __shared__ __align__(16) u16 Ah[32*40], Al[32*40];
  __shared__ __align__(16) u16 B1h[256*40], B1l[256*40];
  __shared__ __align__(16) u16 B2h[256*40], B2l[256*40];
  __shared__ __align__(16) u16 Hh[32*264], Hl[32*264];
  int tid = threadIdx.x;
  int wid = tid>>6, lane = tid&63;
  int wr = wid>>2, wc = wid&3;
  int g = lane>>4, lr = lane&15;
  int rowbase = blockIdx.x*32;
  f32x4 zero = 0.f;
  f32x4 accs[4] = {zero,zero,zero,zero};
  for (int c=0;c<4;c++){
    f32x4 acch[4] = {zero,zero,zero,zero};
    for (int k0=0;k0<M_;k0+=32){
      if (tid < 256){
        int row = tid>>3, q = tid&7;
        float4 v = *(const float4*)(A + (rowbase+row)*M_ + k0 + q*4);
        split4_store(v, Ah + row*40 + q*4, Al + row*40 + q*4);
      }
      #pragma unroll
      for (int it=0; it<4; it++){
        int idx = tid + it*512;
        int row = idx>>3, q = idx&7;
        float4 v = *(const float4*)(W1 + (c*256+row)*M_ + k0 + q*4);
        split4_store(v, B1h + row*40 + q*4, B1l + row*40 + q*4);
      }
      __syncthreads();
      bf16x8 ah = *(const bf16x8*)(Ah + (wr*16 + lr)*40 + g*8);
      bf16x8 al = *(const bf16x8*)(Al + (wr*16 + lr)*40 + g*8);
      #pragma unroll
      for (int j=0;j<4;j++){
        int brow = wc*64 + j*16 + lr;
        bf16x8 bh = *(const bf16x8*)(B1h + brow*40 + g*8);
        bf16x8 bl = *(const bf16x8*)(B1l + brow*40 + g*8);
        acch[j] = mfma3(ah, al, bh, bl, acch[j]);
      }
      __syncthreads();
    }
    // gelu -> H planes
    #pragma unroll
    for (int j=0;j<4;j++){
      #pragma unroll
      for (int r=0;r<4;r++){
        int rl = wr*16 + g*4 + r;
        int fc = wc*64 + j*16 + lr;
        float xv = acch[j][r] + b1[c*256 + fc];
        float gl = 0.5f*xv*(1.f + erff(xv*0.70710678118654752f));
        u16 hi = f2bf(gl);
        u16 lo = f2bf(gl - bf2f(hi));
        Hh[rl*264 + fc] = hi;
        Hl[rl*264 + fc] = lo;
      }
    }
    __syncthreads();
    for (int k0=0;k0<256;k0+=32){
      #pragma unroll
      for (int it=0; it<4; it++){
        int idx = tid + it*512;
        int row = idx>>3, q = idx&7;
        float4 v = *(const float4*)(W2 + row*FF_ + c*256 + k0 + q*4);
        split4_store(v, B2h + row*40 + q*4, B2l + row*40 + q*4);
      }
      __syncthreads();
      bf16x8 ah = *(const bf16x8*)(Hh + (wr*16 + lr)*264 + k0 + g*8);
      bf16x8 al = *(const bf16x8*)(Hl + (wr*16 + lr)*264 + k0 + g*8);
      #pragma unroll
      for (int j=0;j<4;j++){
        int brow = wc*64 + j*16 + lr;
        bf16x8 bh = *(const bf16x8*)(B2h + brow*40 + g*8);
        bf16x8 bl = *(const bf16x8*)(B2l + brow*40 + g*8);
        accs[j] = mfma3(ah, al, bh, bl, accs[j]);
      }
      __syncthreads();
    }
  }
  #pragma unroll
  for (int j=0;j<4;j++){
    #pragma unroll
    for (int r=0;r<4;r++){
      int row = rowbase + wr*16 + g*4 + r;
      int col = wc*64 + j*16 + lr;
      out[row*M_ + col] = accs[j][r] + b2[col];
    }
  }
}

extern "C" void kernel_launch(void* const* d_in, const int* in_sizes, int n_in,
                              void* d_out, int out_size, void* d_ws, size_t ws_size,
                              hipStream_t stream){
  const float* x      = (const float*)d_in[0];
  const float* weight = (const float*)d_in[1];
  const float* wqkv   = (const float*)d_in[2];
  const float* wo     = (const float*)d_in[3];
  const float* ln_g   = (const float*)d_in[4];
  const float* ln_b   = (const float*)d_in[5];
  const float* lnz_g  = (const float*)d_in[6];
  const float* lnz_b  = (const float*)d_in[7];
  const float* fc1_w  = (const float*)d_in[8];
  const float* fc1_b  = (const float*)d_in[9];
  const float* fc2_w  = (const float*)d_in[10];
  const float* fc2_b  = (const float*)d_in[11];
  float* out = (float*)d_out;
  char* ws = (char*)d_ws;
  float* bias  = (float*)(ws + 0);          // 524288 B
  float* wqkvr = (float*)(ws + 524288);     // 3145728 B
  float* P1    = (float*)(ws + 3670016);    // 67108864 B (f32: LN-out -> cumsum -> smid)
  u16*   imv   = (u16*)(ws + 70778880);     // 33554432 B (bf16 pre-scan imv)
  // total 104333312 B (~99.5 MiB)

  k_bias<<<N_, M_, 0, stream>>>(bias);
  k_prep_qkvw2<<<TK_*768, 256, 0, stream>>>(wqkv, wqkvr);
  k_init<<<R_/32, 512, 0, stream>>>(x, weight, bias, out);
  for (int a=0; a<TK_; a++){
    k_ln<<<R_/16, 256, 0, stream>>>(out, ln_g, ln_b, P1);
    k_qkv<<<dim3(R_/32, 2), 512, 0, stream>>>(P1, wqkvr + a*768*M_, imv);
    k_scan<<<L_, 256, 0, stream>>>(imv, P1);
    k_wo<<<R_/32, 512, 0, stream>>>(P1, wo + a*M_*M_, out, lnz_g, lnz_b);
    k_fc<<<R_/32, 512, 0, stream>>>(P1, fc1_w, fc1_b, fc2_w, fc2_b, out);
  }
}

// Round 4
// 2786.554 us; speedup vs baseline: 1.5188x; 1.5188x over previous
//
#include <hip/hip_runtime.h>

typedef unsigned int u32;
typedef unsigned short u16;
typedef __attribute__((ext_vector_type(8))) __bf16 bf16x8;
typedef __attribute__((ext_vector_type(4))) float f32x4;
typedef __attribute__((ext_vector_type(4))) u16 u16x4;

#define L_ 128
#define N_ 512
#define M_ 256
#define TK_ 4
#define H_ 8
#define R_ (L_*N_)
#define FF_ 1024

__device__ __forceinline__ u16 f2bf(float f){
  u32 u = __builtin_bit_cast(u32, f);
  u = (u + 0x7FFFu + ((u>>16)&1u)) >> 16;
  return (u16)u;
}
__device__ __forceinline__ float bf2f(u16 h){ u32 u=((u32)h)<<16; return __builtin_bit_cast(float,u); }
__device__ __forceinline__ f32x4 mfma16(bf16x8 a, bf16x8 b, f32x4 c){
  return __builtin_amdgcn_mfma_f32_16x16x32_bf16(a,b,c,0,0,0);
}
// acc += (ah+al)*(bh+bl), dropping al*bl (~2^-18)
__device__ __forceinline__ f32x4 mfma3(bf16x8 ah, bf16x8 al, bf16x8 bh, bf16x8 bl, f32x4 c){
  c = mfma16(ah, bh, c);
  c = mfma16(al, bh, c);
  c = mfma16(ah, bl, c);
  return c;
}
__device__ __forceinline__ void split4_store(float4 v, u16* hiP, u16* loP){
  u16 h0 = f2bf(v.x), h1 = f2bf(v.y), h2 = f2bf(v.z), h3 = f2bf(v.w);
  u16 l0 = f2bf(v.x - bf2f(h0));
  u16 l1 = f2bf(v.y - bf2f(h1));
  u16 l2 = f2bf(v.z - bf2f(h2));
  u16 l3 = f2bf(v.w - bf2f(h3));
  u16x4 hv, lv;
  hv[0]=h0; hv[1]=h1; hv[2]=h2; hv[3]=h3;
  lv[0]=l0; lv[1]=l1; lv[2]=l2; lv[3]=l3;
  *(u16x4*)hiP = hv;
  *(u16x4*)loP = lv;
}

// ---------------- prep ----------------
__global__ void k_bias(float* __restrict__ bias){
  int j = blockIdx.x, l = threadIdx.x;
  int t = l>>1;
  float base = expf(-0.14391156831212757f * (float)t); // ln(10000)/64
  float ang = (float)j * base;
  bias[j*M_ + l] = (l&1) ? cosf(ang) : sinf(ang);
}

// generic f32 -> hi/lo bf16 planes
__global__ void k_split(const float* __restrict__ src, u16* __restrict__ hi, u16* __restrict__ lo, int n4){
  int i = blockIdx.x*256 + threadIdx.x;
  if (i < n4){
    float4 v = ((const float4*)src)[i];
    split4_store(v, hi + i*4, lo + i*4);
  }
}

// Wqkv[a,x,h,d,m] -> planes [a][h*96 + x*32 + d][m]
__global__ void k_split_qkv(const float* __restrict__ w, u16* __restrict__ hi, u16* __restrict__ lo){
  int b = blockIdx.x, m = threadIdx.x;
  int a = b/768, colp = b%768;
  int h = colp/96, rem = colp%96, x = rem/32, d = rem&31;
  float v = w[(((a*3 + x)*H_ + h)*32 + d)*M_ + m];
  u16 hv = f2bf(v);
  hi[b*M_ + m] = hv;
  lo[b*M_ + m] = f2bf(v - bf2f(hv));
}

// ---------------- k_init: out = x @ weight^T + bias ----------------
__global__ __launch_bounds__(512) void k_init(const float* __restrict__ X,
    const u16* __restrict__ Wh_g, const u16* __restrict__ Wl_g,
    const float* __restrict__ bias, float* __restrict__ out){
  __shared__ __align__(16) u16 Ah[32*40], Al[32*40];
  __shared__ __align__(16) u16 Bh[256*40], Bl[256*40];
  int tid = threadIdx.x;
  int wid = tid>>6, lane = tid&63;
  int wr = wid>>2, wc = wid&3;
  int g = lane>>4, lr = lane&15;
  int rowbase = blockIdx.x*32;
  f32x4 zero = 0.f;
  f32x4 acc[4] = {zero,zero,zero,zero};
  for (int k0=0;k0<M_;k0+=32){
    if (tid < 256){
      int row = tid>>3, q = tid&7;
      float4 v = *(const float4*)(X + (rowbase+row)*M_ + k0 + q*4);
      split4_store(v, Ah + row*40 + q*4, Al + row*40 + q*4);
    }
    #pragma unroll
    for (int it=0; it<4; it++){
      int idx = tid + (it&1)*512;      // 0..1023
      int row = idx>>2, q = idx&3;
      const u16* s = ((it<2)? Wh_g : Wl_g) + row*M_ + k0 + q*8;
      u16* d = ((it<2)? Bh : Bl) + row*40 + q*8;
      *(uint4*)d = *(const uint4*)s;
    }
    __syncthreads();
    bf16x8 ah = *(const bf16x8*)(Ah + (wr*16 + lr)*40 + g*8);
    bf16x8 al = *(const bf16x8*)(Al + (wr*16 + lr)*40 + g*8);
    #pragma unroll
    for (int j=0;j<4;j++){
      int brow = wc*64 + j*16 + lr;
      bf16x8 bh = *(const bf16x8*)(Bh + brow*40 + g*8);
      bf16x8 bl = *(const bf16x8*)(Bl + brow*40 + g*8);
      acc[j] = mfma3(ah, al, bh, bl, acc[j]);
    }
    __syncthreads();
  }
  #pragma unroll
  for (int j=0;j<4;j++){
    #pragma unroll
    for (int r=0;r<4;r++){
      int row = rowbase + wr*16 + g*4 + r;
      int col = wc*64 + j*16 + lr;
      out[row*M_ + col] = acc[j][r] + bias[(row & (N_-1))*M_ + col];
    }
  }
}

// ---------------- LN(s) -> hi/lo planes ----------------
__global__ __launch_bounds__(256) void k_ln(const float* __restrict__ s, const float* __restrict__ lg,
    const float* __restrict__ lb, u16* __restrict__ P1h, u16* __restrict__ P1l){
  int tid = threadIdx.x;
  int rl = tid>>4, c16 = tid&15;
  int row = blockIdx.x*16 + rl;
  const float* sr = s + row*M_ + c16*16;
  float v[16];
  #pragma unroll
  for (int q=0;q<4;q++){
    float4 t = ((const float4*)sr)[q];
    v[q*4+0]=t.x; v[q*4+1]=t.y; v[q*4+2]=t.z; v[q*4+3]=t.w;
  }
  float sum=0.f, sq=0.f;
  #pragma unroll
  for (int e=0;e<16;e++){ sum+=v[e]; sq+=v[e]*v[e]; }
  #pragma unroll
  for (int o=1;o<16;o<<=1){ sum += __shfl_xor(sum,o); sq += __shfl_xor(sq,o); }
  float mean = sum*(1.f/M_);
  float var  = sq*(1.f/M_) - mean*mean;
  float rstd = rsqrtf(var + 1e-5f);
  #pragma unroll
  for (int q=0;q<4;q++){
    int col = c16*16 + q*4;
    float4 o;
    o.x = (v[q*4+0]-mean)*rstd*lg[col+0] + lb[col+0];
    o.y = (v[q*4+1]-mean)*rstd*lg[col+1] + lb[col+1];
    o.z = (v[q*4+2]-mean)*rstd*lg[col+2] + lb[col+2];
    o.w = (v[q*4+3]-mean)*rstd*lg[col+3] + lb[col+3];
    split4_store(o, P1h + row*M_ + col, P1l + row*M_ + col);
  }
}

// ---------------- QKV GEMM + fused rsa -> imv(bf16) written in-place into P1h ----------------
// 32 rows/block, 8 waves = 8 heads, full 768-row B tile staged per k-chunk
__global__ __launch_bounds__(512) void k_qkv(const u16* __restrict__ Ah_g, const u16* __restrict__ Al_g,
    const u16* __restrict__ Wh_g, const u16* __restrict__ Wl_g, u16* __restrict__ P1h){
  __shared__ __align__(16) u16 Ah[32*40], Al[32*40];
  __shared__ __align__(16) u16 Bh[768*40], Bl[768*40];
  int tid = threadIdx.x;
  int wid = tid>>6, lane = tid&63;
  int h = wid;
  int g = lane>>4, lr = lane&15;
  int rowbase = blockIdx.x*32;
  f32x4 zero = 0.f;
  f32x4 acc[2][6];
  #pragma unroll
  for (int rf=0;rf<2;rf++)
    #pragma unroll
    for (int c=0;c<6;c++) acc[rf][c] = zero;
  for (int k0=0;k0<M_;k0+=32){
    if (tid < 256){
      int plane = tid>>7, rem = tid&127;
      int row = rem>>2, q = rem&3;
      const u16* s = (plane? Al_g : Ah_g) + (rowbase+row)*M_ + k0 + q*8;
      u16* d = (plane? Al : Ah) + row*40 + q*8;
      *(uint4*)d = *(const uint4*)s;
    }
    #pragma unroll
    for (int it=0; it<12; it++){
      int idx = tid + (it<6 ? it : it-6)*512;   // 0..3071
      int row = idx>>2, q = idx&3;
      const u16* s = ((it<6)? Wh_g : Wl_g) + row*M_ + k0 + q*8;
      u16* d = ((it<6)? Bh : Bl) + row*40 + q*8;
      *(uint4*)d = *(const uint4*)s;
    }
    __syncthreads();
    #pragma unroll
    for (int rf=0;rf<2;rf++){
      bf16x8 ah = *(const bf16x8*)(Ah + (rf*16 + lr)*40 + g*8);
      bf16x8 al = *(const bf16x8*)(Al + (rf*16 + lr)*40 + g*8);
      #pragma unroll
      for (int c=0;c<6;c++){
        int brow = h*96 + c*16 + lr;
        bf16x8 bh = *(const bf16x8*)(Bh + brow*40 + g*8);
        bf16x8 bl = *(const bf16x8*)(Bl + brow*40 + g*8);
        acc[rf][c] = mfma3(ah, al, bh, bl, acc[rf][c]);
      }
    }
    __syncthreads();
  }
  const float isd = 0.17677669529663687f; // 1/sqrt(32)
  #pragma unroll
  for (int rf=0;rf<2;rf++){
    f32x4 p = acc[rf][0]*acc[rf][2] + acc[rf][1]*acc[rf][3];
    #pragma unroll
    for (int r=0;r<4;r++){
      float v = p[r];
      v += __shfl_xor(v,1); v += __shfl_xor(v,2);
      v += __shfl_xor(v,4); v += __shfl_xor(v,8);
      float rsa = v * isd;
      int row = rowbase + rf*16 + g*4 + r;
      #pragma unroll
      for (int c2=0;c2<2;c2++){
        P1h[row*M_ + h*32 + c2*16 + lr] = f2bf(rsa*acc[rf][4+c2][r]);
      }
    }
  }
}

// ---------------- cumsum over j: P1h(bf16 imv) -> P1h/P1l (split cumsum) ----------------
__global__ void k_scan(u16* __restrict__ P1h, u16* __restrict__ P1l){
  int i = blockIdx.x, m = threadIdx.x;
  int base = i*N_*M_ + m;
  float acc = 0.f;
  for (int jb=0; jb<N_; jb+=8){
    float t[8];
    #pragma unroll
    for (int u=0;u<8;u++) t[u] = bf2f(P1h[base + (jb+u)*M_]);
    #pragma unroll
    for (int u=0;u<8;u++){
      acc += t[u];
      u16 hv = f2bf(acc);
      P1h[base + (jb+u)*M_] = hv;
      P1l[base + (jb+u)*M_] = f2bf(acc - bf2f(hv));
    }
  }
}

// ---------------- Wo GEMM + s_old + LN + residual -> smid planes (in-place into P1) ----------------
__global__ __launch_bounds__(512) void k_wo(u16* __restrict__ P1h, u16* __restrict__ P1l,
    const u16* __restrict__ Wh_g, const u16* __restrict__ Wl_g,
    const float* __restrict__ sold, const float* __restrict__ lg, const float* __restrict__ lb){
  __shared__ __align__(16) u16 Ah[32*264], Al[32*264];
  __shared__ __align__(16) u16 Bh[256*40], Bl[256*40];
  __shared__ float zs[32][257];
  int tid = threadIdx.x;
  int wid = tid>>6, lane = tid&63;
  int wr = wid>>2, wc = wid&3;
  int g = lane>>4, lr = lane&15;
  int rowbase = blockIdx.x*32;
  // stage ALL of A (cumsum rows, both planes) upfront -> allows in-place write at end
  #pragma unroll
  for (int it=0; it<4; it++){
    int idx = tid + (it&1)*512;   // 0..1023
    int row = idx>>5, q = idx&31;
    const u16* s = ((it<2)? P1h : P1l) + (rowbase+row)*M_ + q*8;
    u16* d = ((it<2)? Ah : Al) + row*264 + q*8;
    *(uint4*)d = *(const uint4*)s;
  }
  f32x4 zero = 0.f;
  f32x4 acc[4] = {zero,zero,zero,zero};
  for (int k0=0;k0<M_;k0+=32){
    #pragma unroll
    for (int it=0; it<4; it++){
      int idx = tid + (it&1)*512;
      int row = idx>>2, q = idx&3;
      const u16* s = ((it<2)? Wh_g : Wl_g) + row*M_ + k0 + q*8;
      u16* d = ((it<2)? Bh : Bl) + row*40 + q*8;
      *(uint4*)d = *(const uint4*)s;
    }
    __syncthreads();
    bf16x8 ah = *(const bf16x8*)(Ah + (wr*16 + lr)*264 + k0 + g*8);
    bf16x8 al = *(const bf16x8*)(Al + (wr*16 + lr)*264 + k0 + g*8);
    #pragma unroll
    for (int j=0;j<4;j++){
      int brow = wc*64 + j*16 + lr;
      bf16x8 bh = *(const bf16x8*)(Bh + brow*40 + g*8);
      bf16x8 bl = *(const bf16x8*)(Bl + brow*40 + g*8);
      acc[j] = mfma3(ah, al, bh, bl, acc[j]);
    }
    __syncthreads();
  }
  #pragma unroll
  for (int j=0;j<4;j++){
    #pragma unroll
    for (int r=0;r<4;r++){
      int rl = wr*16 + g*4 + r;
      int col = wc*64 + j*16 + lr;
      zs[rl][col] = acc[j][r] + sold[(rowbase+rl)*M_ + col];
    }
  }
  __syncthreads();
  int rl2 = tid>>4, c16 = tid&15;
  float sum=0.f, sq=0.f;
  float v[16];
  #pragma unroll
  for (int e=0;e<16;e++){ v[e] = zs[rl2][c16*16+e]; sum+=v[e]; sq+=v[e]*v[e]; }
  #pragma unroll
  for (int o=1;o<16;o<<=1){ sum += __shfl_xor(sum,o); sq += __shfl_xor(sq,o); }
  float mean = sum*(1.f/M_);
  float var  = sq*(1.f/M_) - mean*mean;
  float rstd = rsqrtf(var + 1e-5f);
  int rowo = rowbase + rl2;
  #pragma unroll
  for (int q=0;q<4;q++){
    int col = c16*16 + q*4;
    float4 o;
    o.x = (v[q*4+0]-mean)*rstd*lg[col+0] + lb[col+0] + v[q*4+0];
    o.y = (v[q*4+1]-mean)*rstd*lg[col+1] + lb[col+1] + v[q*4+1];
    o.z = (v[q*4+2]-mean)*rstd*lg[col+2] + lb[col+2] + v[q*4+2];
    o.w = (v[q*4+3]-mean)*rstd*lg[col+3] + lb[col+3] + v[q*4+3];
    split4_store(o, P1h + rowo*M_ + col, P1l + rowo*M_ + col);
  }
}

// ---------------- fused MLP: gelu(smid@fc1^T+b1)@fc2^T + b2 -> out ----------------
// 64 rows/block, 8 waves = 2 wr x 4 wc, B buffer shared by FC1/FC2 phases
__global__ __launch_bounds__(512) void k_fc(const u16* __restrict__ Ah_g, const u16* __restrict__ Al_g,
    const u16* __restrict__ W1h, const u16* __restrict__ W1l, const float* __restrict__ b1,
    const u16* __restrict__ W2h, const u16* __restrict__ W2l, const float* __restrict__ b2,
    float* __restrict__ out){
  __shared__ __align__(16) u16 Ah[64*40], Al[64*40];
  __shared__ __align__(16) u16 Bh[256*40], Bl[256*40];
  __shared__ __align__(16) u16 Hh[64*264], Hl[64*264];
  int tid = threadIdx.x;
  int wid = tid>>6, lane = tid&63;
  int wr = wid>>2, wc = wid&3;     // wr 0..1 (32 rows), wc 0..3 (64 cols)
  int g = lane>>4, lr = lane&15;
  int rowbase = blockIdx.x*64;
  f32x4 zero = 0.f;
  f32x4 acc2[2][4];
  #pragma unroll
  for (int rf=0;rf<2;rf++)
    #pragma unroll
    for (int j=0;j<4;j++) acc2[rf][j] = zero;
  for (int c=0;c<4;c++){
    f32x4 acc1[2][4];
    #pragma unroll
    for (int rf=0;rf<2;rf++)
      #pragma unroll
      for (int j=0;j<4;j++) acc1[rf][j] = zero;
    // ---- FC1 chunk: cols [c*256, c*256+256) ----
    for (int k0=0;k0<M_;k0+=32){
      { // stage A: 64 rows x 32k x 2 planes = 512 chunks
        int plane = tid>>8, rem = tid&255;
        int row = rem>>2, q = rem&3;
        const u16* s = (plane? Al_g : Ah_g) + (rowbase+row)*M_ + k0 + q*8;
        u16* d = (plane? Al : Ah) + row*40 + q*8;
        *(uint4*)d = *(const uint4*)s;
      }
      #pragma unroll
      for (int it=0; it<4; it++){  // stage B1
        int idx = tid + (it&1)*512;
        int row = idx>>2, q = idx&3;
        const u16* s = ((it<2)? W1h : W1l) + (c*256+row)*M_ + k0 + q*8;
        u16* d = ((it<2)? Bh : Bl) + row*40 + q*8;
        *(uint4*)d = *(const uint4*)s;
      }
      __syncthreads();
      bf16x8 ah[2], al[2];
      #pragma unroll
      for (int rf=0;rf<2;rf++){
        ah[rf] = *(const bf16x8*)(Ah + (wr*32 + rf*16 + lr)*40 + g*8);
        al[rf] = *(const bf16x8*)(Al + (wr*32 + rf*16 + lr)*40 + g*8);
      }
      #pragma unroll
      for (int j=0;j<4;j++){
        int brow = wc*64 + j*16 + lr;
        bf16x8 bh = *(const bf16x8*)(Bh + brow*40 + g*8);
        bf16x8 bl = *(const bf16x8*)(Bl + brow*40 + g*8);
        #pragma unroll
        for (int rf=0;rf<2;rf++)
          acc1[rf][j] = mfma3(ah[rf], al[rf], bh, bl, acc1[rf][j]);
      }
      __syncthreads();
    }
    // ---- gelu -> H planes ----
    #pragma unroll
    for (int rf=0;rf<2;rf++){
      #pragma unroll
      for (int j=0;j<4;j++){
        #pragma unroll
        for (int r=0;r<4;r++){
          int rl = wr*32 + rf*16 + g*4 + r;
          int fcol = wc*64 + j*16 + lr;
          float xv = acc1[rf][j][r] + b1[c*256 + fcol];
          float gl = 0.5f*xv*(1.f + erff(xv*0.70710678118654752f));
          u16 hv = f2bf(gl);
          Hh[rl*264 + fcol] = hv;
          Hl[rl*264 + fcol] = f2bf(gl - bf2f(hv));
        }
      }
    }
    __syncthreads();
    // ---- FC2 partial: k-range [c*256, c*256+256) ----
    for (int k0=0;k0<M_;k0+=32){
      #pragma unroll
      for (int it=0; it<4; it++){  // stage B2 (reuse B buffers)
        int idx = tid + (it&1)*512;
        int row = idx>>2, q = idx&3;
        const u16* s = ((it<2)? W2h : W2l) + row*FF_ + c*256 + k0 + q*8;
        u16* d = ((it<2)? Bh : Bl) + row*40 + q*8;
        *(uint4*)d = *(const uint4*)s;
      }
      __syncthreads();
      bf16x8 ha[2], hl[2];
      #pragma unroll
      for (int rf=0;rf<2;rf++){
        ha[rf] = *(const bf16x8*)(Hh + (wr*32 + rf*16 + lr)*264 + k0 + g*8);
        hl[rf] = *(const bf16x8*)(Hl + (wr*32 + rf*16 + lr)*264 + k0 + g*8);
      }
      #pragma unroll
      for (int j=0;j<4;j++){
        int brow = wc*64 + j*16 + lr;
        bf16x8 bh = *(const bf16x8*)(Bh + brow*40 + g*8);
        bf16x8 bl = *(const bf16x8*)(Bl + brow*40 + g*8);
        #pragma unroll
        for (int rf=0;rf<2;rf++)
          acc2[rf][j] = mfma3(ha[rf], hl[rf], bh, bl, acc2[rf][j]);
      }
      __syncthreads();
    }
  }
  #pragma unroll
  for (int rf=0;rf<2;rf++){
    #pragma unroll
    for (int j=0;j<4;j++){
      #pragma unroll
      for (int r=0;r<4;r++){
        int row = rowbase + wr*32 + rf*16 + g*4 + r;
        int col = wc*64 + j*16 + lr;
        out[row*M_ + col] = acc2[rf][j][r] + b2[col];
      }
    }
  }
}

extern "C" void kernel_launch(void* const* d_in, const int* in_sizes, int n_in,
                              void* d_out, int out_size, void* d_ws, size_t ws_size,
                              hipStream_t stream){
  const float* x      = (const float*)d_in[0];
  const float* weight = (const float*)d_in[1];
  const float* wqkv   = (const float*)d_in[2];
  const float* wo     = (const float*)d_in[3];
  const float* ln_g   = (const float*)d_in[4];
  const float* ln_b   = (const float*)d_in[5];
  const float* lnz_g  = (const float*)d_in[6];
  const float* lnz_b  = (const float*)d_in[7];
  const float* fc1_w  = (const float*)d_in[8];
  const float* fc1_b  = (const float*)d_in[9];
  const float* fc2_w  = (const float*)d_in[10];
  const float* fc2_b  = (const float*)d_in[11];
  float* out = (float*)d_out;
  char* ws = (char*)d_ws;
  size_t off = 0;
  float* bias  = (float*)(ws + off); off += 524288;
  u16* weight_h = (u16*)(ws + off); off += 131072;
  u16* weight_l = (u16*)(ws + off); off += 131072;
  u16* wqkv_h   = (u16*)(ws + off); off += 1572864;
  u16* wqkv_l   = (u16*)(ws + off); off += 1572864;
  u16* wo_h     = (u16*)(ws + off); off += 524288;
  u16* wo_l     = (u16*)(ws + off); off += 524288;
  u16* fc1_h    = (u16*)(ws + off); off += 524288;
  u16* fc1_l    = (u16*)(ws + off); off += 524288;
  u16* fc2_h    = (u16*)(ws + off); off += 524288;
  u16* fc2_l    = (u16*)(ws + off); off += 524288;
  u16* P1h      = (u16*)(ws + off); off += 33554432;
  u16* P1l      = (u16*)(ws + off); off += 33554432;
  // total 74,186,752 B (~70.8 MiB)

  k_bias<<<N_, M_, 0, stream>>>(bias);
  k_split<<<64, 256, 0, stream>>>(weight, weight_h, weight_l, 65536/4);
  k_split_qkv<<<TK_*768, 256, 0, stream>>>(wqkv, wqkv_h, wqkv_l);
  k_split<<<256, 256, 0, stream>>>(wo, wo_h, wo_l, 262144/4);
  k_split<<<256, 256, 0, stream>>>(fc1_w, fc1_h, fc1_l, 262144/4);
  k_split<<<256, 256, 0, stream>>>(fc2_w, fc2_h, fc2_l, 262144/4);
  k_init<<<R_/32, 512, 0, stream>>>(x, weight_h, weight_l, bias, out);
  for (int a=0; a<TK_; a++){
    k_ln<<<R_/16, 256, 0, stream>>>(out, ln_g, ln_b, P1h, P1l);
    k_qkv<<<R_/32, 512, 0, stream>>>(P1h, P1l, wqkv_h + a*768*M_, wqkv_l + a*768*M_, P1h);
    k_scan<<<L_, 256, 0, stream>>>(P1h, P1l);
    k_wo<<<R_/32, 512, 0, stream>>>(P1h, P1l, wo_h + a*65536, wo_l + a*65536, out, lnz_g, lnz_b);
    k_fc<<<R_/64, 512, 0, stream>>>(P1h, P1l, fc1_h, fc1_l, fc1_b, fc2_h, fc2_l, fc2_b, out);
  }
}

// Round 5
// 1698.475 us; speedup vs baseline: 2.4918x; 1.6406x over previous
//
#include <hip/hip_runtime.h>

typedef unsigned int u32;
typedef unsigned short u16;
typedef _Float16 f16;
typedef __attribute__((ext_vector_type(8))) _Float16 f16x8;
typedef __attribute__((ext_vector_type(4))) float f32x4;
typedef __attribute__((ext_vector_type(4))) u16 u16x4;

#define L_ 128
#define N_ 512
#define M_ 256
#define TK_ 4
#define H_ 8
#define R_ (L_*N_)
#define FF_ 1024

__device__ __forceinline__ u16 f2h(float v){ f16 h=(f16)v; return __builtin_bit_cast(u16,h); }
__device__ __forceinline__ float h2f(u16 b){ return (float)__builtin_bit_cast(f16,b); }
__device__ __forceinline__ f32x4 mfmah(f16x8 a, f16x8 b, f32x4 c){
  return __builtin_amdgcn_mfma_f32_16x16x32_f16(a,b,c,0,0,0);
}
// LDS tile formats (all XOR-swizzled, K-chunk = 64):
//  A (split):  [row][16 slots of 8 halves]  row stride 128 u16 (256B); slot = p*8 + (st*4+g); low3 ^= row&7
//  B (single): [row][8 slots]               row stride 64 u16 (128B);  slot = st*4+g; ^= row&7
__device__ __forceinline__ f16x8 afrag(const u16* buf, int row, int p, int st, int g){
  int sl = (p<<3) | ((((st<<2)|g) ^ row) & 7);
  return *(const f16x8*)(buf + row*128 + sl*8);
}
__device__ __forceinline__ f16x8 bfrag(const u16* buf, int row, int st, int g){
  int sl = (((st<<2)|g) ^ row) & 7;
  return *(const f16x8*)(buf + row*64 + sl*8);
}

// ---------------- prep ----------------
__global__ void k_bias(float* __restrict__ bias){
  int j = blockIdx.x, l = threadIdx.x;
  int t = l>>1;
  float base = expf(-0.14391156831212757f * (float)t); // ln(10000)/64
  float ang = (float)j * base;
  bias[j*M_ + l] = (l&1) ? cosf(ang) : sinf(ang);
}

__global__ void k_half(const float* __restrict__ src, u16* __restrict__ dst, int n4){
  int i = blockIdx.x*256 + threadIdx.x;
  if (i < n4){
    float4 v = ((const float4*)src)[i];
    u16x4 o;
    o[0]=f2h(v.x); o[1]=f2h(v.y); o[2]=f2h(v.z); o[3]=f2h(v.w);
    *(u16x4*)(dst + i*4) = o;
  }
}

// Wqkv[a,x,hd,d,m] -> f16 [a][hd*96 + x*32 + d][m]
__global__ void k_half_qkv(const float* __restrict__ w, u16* __restrict__ dst){
  int b = blockIdx.x, m = threadIdx.x;
  int a = b/768, colp = b%768;
  int hd = colp/96, rem = colp%96, x = rem/32, d = rem&31;
  dst[b*M_ + m] = f2h(w[(((a*3 + x)*H_ + hd)*32 + d)*M_ + m]);
}

// ---------------- k_init: out = x @ weight^T + bias ----------------
__global__ __launch_bounds__(512) void k_init(const float* __restrict__ X, const u16* __restrict__ Wh,
    const float* __restrict__ bias, float* __restrict__ out){
  __shared__ __align__(16) u16 Abuf[64*128];
  __shared__ __align__(16) u16 Bbuf[256*64];
  int tid = threadIdx.x;
  int wid = tid>>6, lane = tid&63;
  int wr = wid>>2, wc = wid&3;
  int g = lane>>4, lr = lane&15;
  int rowbase = blockIdx.x*64;
  f32x4 acc[2][4];
  #pragma unroll
  for (int rf=0;rf<2;rf++)
    #pragma unroll
    for (int j=0;j<4;j++) acc[rf][j] = 0.f;
  for (int k0=0;k0<M_;k0+=64){
    { // A stage from f32 with in-kernel split: 64 rows x 8 kgroups = 512 chunks
      int row = tid>>3, s = tid&7;
      const float* sp = X + (rowbase+row)*M_ + k0 + s*8;
      float4 v0 = *(const float4*)sp, v1 = *(const float4*)(sp+4);
      float vv[8] = {v0.x,v0.y,v0.z,v0.w,v1.x,v1.y,v1.z,v1.w};
      f16x8 hv, lv;
      #pragma unroll
      for (int e=0;e<8;e++){ f16 h=(f16)vv[e]; hv[e]=h; lv[e]=(f16)(vv[e]-(float)h); }
      int sl = s ^ (row&7);
      *(f16x8*)(Abuf + row*128 + sl*8) = hv;
      *(f16x8*)(Abuf + row*128 + (8|sl)*8) = lv;
    }
    #pragma unroll
    for (int it=0; it<4; it++){ // B: 256 rows x 8 slots
      int idx = tid + it*512; int row = idx>>3, s = idx&7;
      int ss = (s ^ row) & 7;
      *(uint4*)(Bbuf + row*64 + ss*8) = *(const uint4*)(Wh + row*M_ + k0 + s*8);
    }
    __syncthreads();
    #pragma unroll
    for (int st=0; st<2; st++){
      f16x8 ah[2], al[2], bf[4];
      #pragma unroll
      for (int rf=0;rf<2;rf++){ int ar = wr*32 + rf*16 + lr; ah[rf]=afrag(Abuf,ar,0,st,g); al[rf]=afrag(Abuf,ar,1,st,g); }
      #pragma unroll
      for (int j=0;j<4;j++){ int br = wc*64 + j*16 + lr; bf[j]=bfrag(Bbuf,br,st,g); }
      #pragma unroll
      for (int rf=0;rf<2;rf++)
        #pragma unroll
        for (int j=0;j<4;j++){
          acc[rf][j] = mfmah(ah[rf], bf[j], acc[rf][j]);
          acc[rf][j] = mfmah(al[rf], bf[j], acc[rf][j]);
        }
    }
    __syncthreads();
  }
  #pragma unroll
  for (int rf=0;rf<2;rf++)
    #pragma unroll
    for (int j=0;j<4;j++)
      #pragma unroll
      for (int r=0;r<4;r++){
        int row = rowbase + wr*32 + rf*16 + g*4 + r;
        int col = wc*64 + j*16 + lr;
        out[row*M_ + col] = acc[rf][j][r] + bias[(row & (N_-1))*M_ + col];
      }
}

// ---------------- LN(s) -> f16 hi/lo planes ----------------
__global__ __launch_bounds__(256) void k_ln(const float* __restrict__ s, const float* __restrict__ lg,
    const float* __restrict__ lb, u16* __restrict__ P1h, u16* __restrict__ P1l){
  int tid = threadIdx.x;
  int rl = tid>>4, c16 = tid&15;
  int row = blockIdx.x*16 + rl;
  const float* sr = s + row*M_ + c16*16;
  float v[16];
  #pragma unroll
  for (int q=0;q<4;q++){
    float4 t = ((const float4*)sr)[q];
    v[q*4+0]=t.x; v[q*4+1]=t.y; v[q*4+2]=t.z; v[q*4+3]=t.w;
  }
  float sum=0.f, sq=0.f;
  #pragma unroll
  for (int e=0;e<16;e++){ sum+=v[e]; sq+=v[e]*v[e]; }
  #pragma unroll
  for (int o=1;o<16;o<<=1){ sum += __shfl_xor(sum,o); sq += __shfl_xor(sq,o); }
  float mean = sum*(1.f/M_);
  float var  = sq*(1.f/M_) - mean*mean;
  float rstd = rsqrtf(var + 1e-5f);
  #pragma unroll
  for (int q=0;q<4;q++){
    int col = c16*16 + q*4;
    u16x4 hv, lv;
    #pragma unroll
    for (int e=0;e<4;e++){
      float o = (v[q*4+e]-mean)*rstd*lg[col+e] + lb[col+e];
      u16 hb = f2h(o);
      hv[e] = hb;
      lv[e] = f2h(o - h2f(hb));
    }
    *(u16x4*)(P1h + row*M_ + col) = hv;
    *(u16x4*)(P1l + row*M_ + col) = lv;
  }
}

// ---------------- QKV GEMM + fused rsa -> imv (f16) ----------------
// grid (R/64, 2); 64 rows/block, 4 heads/block; wave = (head, rowhalf)
__global__ __launch_bounds__(512) void k_qkv(const u16* __restrict__ Ph, const u16* __restrict__ Pl,
    const u16* __restrict__ Wq, u16* __restrict__ imv){
  __shared__ __align__(16) u16 Abuf[64*128];
  __shared__ __align__(16) u16 Bbuf[384*64];
  int tid = threadIdx.x;
  int wid = tid>>6, lane = tid&63;
  int hd = wid>>1, sub = wid&1;
  int g = lane>>4, lr = lane&15;
  int rowbase = blockIdx.x*64;
  int hbase = blockIdx.y*384;
  f32x4 acc[2][6];
  #pragma unroll
  for (int rf=0;rf<2;rf++)
    #pragma unroll
    for (int c=0;c<6;c++) acc[rf][c] = 0.f;
  for (int k0=0;k0<M_;k0+=64){
    #pragma unroll
    for (int it=0; it<2; it++){ // A: 64 rows x 16 slots
      int idx = tid + it*512; int row = idx>>4, s = idx&15;
      const u16* src = (s<8 ? Ph : Pl) + (rowbase+row)*M_ + k0 + (s&7)*8;
      int ss = (s&8) | ((s ^ row) & 7);
      *(uint4*)(Abuf + row*128 + ss*8) = *(const uint4*)src;
    }
    #pragma unroll
    for (int it=0; it<6; it++){ // B: 384 rows x 8 slots
      int idx = tid + it*512; int row = idx>>3, s = idx&7;
      int ss = (s ^ row) & 7;
      *(uint4*)(Bbuf + row*64 + ss*8) = *(const uint4*)(Wq + (hbase+row)*M_ + k0 + s*8);
    }
    __syncthreads();
    #pragma unroll
    for (int st=0; st<2; st++){
      f16x8 ah[2], al[2];
      #pragma unroll
      for (int rf=0;rf<2;rf++){ int ar = sub*32 + rf*16 + lr; ah[rf]=afrag(Abuf,ar,0,st,g); al[rf]=afrag(Abuf,ar,1,st,g); }
      #pragma unroll
      for (int c=0;c<6;c++){
        int br = hd*96 + c*16 + lr;
        f16x8 bf = bfrag(Bbuf,br,st,g);
        #pragma unroll
        for (int rf=0;rf<2;rf++){
          acc[rf][c] = mfmah(ah[rf], bf, acc[rf][c]);
          acc[rf][c] = mfmah(al[rf], bf, acc[rf][c]);
        }
      }
    }
    __syncthreads();
  }
  const float isd = 0.17677669529663687f; // 1/sqrt(32)
  int head = blockIdx.y*4 + hd;
  #pragma unroll
  for (int rf=0;rf<2;rf++){
    f32x4 p = acc[rf][0]*acc[rf][2] + acc[rf][1]*acc[rf][3];
    #pragma unroll
    for (int r=0;r<4;r++){
      float v = p[r];
      v += __shfl_xor(v,1); v += __shfl_xor(v,2);
      v += __shfl_xor(v,4); v += __shfl_xor(v,8);
      float rsa = v * isd;
      int row = rowbase + sub*32 + rf*16 + g*4 + r;
      #pragma unroll
      for (int c2=0;c2<2;c2++){
        imv[row*M_ + head*32 + c2*16 + lr] = f2h(rsa*acc[rf][4+c2][r]);
      }
    }
  }
}

// ---------------- cumsum over j: imv(f16) -> P1h/P1l split ----------------
__global__ void k_scan(const u16* __restrict__ imv, u16* __restrict__ P1h, u16* __restrict__ P1l){
  int i = blockIdx.x, m = threadIdx.x;
  int base = i*N_*M_ + m;
  float acc = 0.f;
  for (int jb=0; jb<N_; jb+=8){
    float t[8];
    #pragma unroll
    for (int u=0;u<8;u++) t[u] = h2f(imv[base + (jb+u)*M_]);
    #pragma unroll
    for (int u=0;u<8;u++){
      acc += t[u];
      u16 hv = f2h(acc);
      P1h[base + (jb+u)*M_] = hv;
      P1l[base + (jb+u)*M_] = f2h(acc - h2f(hv));
    }
  }
}

// ---------------- Wo GEMM + s_old + LN + residual -> P1 planes (in-place) ----------------
__global__ __launch_bounds__(512) void k_wo(u16* __restrict__ P1h, u16* __restrict__ P1l,
    const u16* __restrict__ Wh, const float* __restrict__ sold,
    const float* __restrict__ lg, const float* __restrict__ lb){
  __shared__ __align__(16) u16 Abuf[64*128];
  __shared__ __align__(16) u16 Bbuf[256*64];
  __shared__ float zs[4][64][2];
  int tid = threadIdx.x;
  int wid = tid>>6, lane = tid&63;
  int wr = wid>>2, wc = wid&3;
  int g = lane>>4, lr = lane&15;
  int rowbase = blockIdx.x*64;
  f32x4 acc[2][4];
  #pragma unroll
  for (int rf=0;rf<2;rf++)
    #pragma unroll
    for (int j=0;j<4;j++) acc[rf][j] = 0.f;
  for (int k0=0;k0<M_;k0+=64){
    #pragma unroll
    for (int it=0; it<2; it++){
      int idx = tid + it*512; int row = idx>>4, s = idx&15;
      const u16* src = (s<8 ? P1h : P1l) + (rowbase+row)*M_ + k0 + (s&7)*8;
      int ss = (s&8) | ((s ^ row) & 7);
      *(uint4*)(Abuf + row*128 + ss*8) = *(const uint4*)src;
    }
    #pragma unroll
    for (int it=0; it<4; it++){
      int idx = tid + it*512; int row = idx>>3, s = idx&7;
      int ss = (s ^ row) & 7;
      *(uint4*)(Bbuf + row*64 + ss*8) = *(const uint4*)(Wh + row*M_ + k0 + s*8);
    }
    __syncthreads();
    #pragma unroll
    for (int st=0; st<2; st++){
      f16x8 ah[2], al[2], bf[4];
      #pragma unroll
      for (int rf=0;rf<2;rf++){ int ar = wr*32 + rf*16 + lr; ah[rf]=afrag(Abuf,ar,0,st,g); al[rf]=afrag(Abuf,ar,1,st,g); }
      #pragma unroll
      for (int j=0;j<4;j++){ int br = wc*64 + j*16 + lr; bf[j]=bfrag(Bbuf,br,st,g); }
      #pragma unroll
      for (int rf=0;rf<2;rf++)
        #pragma unroll
        for (int j=0;j<4;j++){
          acc[rf][j] = mfmah(ah[rf], bf[j], acc[rf][j]);
          acc[rf][j] = mfmah(al[rf], bf[j], acc[rf][j]);
        }
    }
    __syncthreads();
  }
  // z = acc + sold; row-wise LN stats via shfl + tiny LDS cross-wave reduce
  float z[2][4][4];
  #pragma unroll
  for (int rf=0;rf<2;rf++)
    #pragma unroll
    for (int j=0;j<4;j++)
      #pragma unroll
      for (int r=0;r<4;r++){
        int row = rowbase + wr*32 + rf*16 + g*4 + r;
        int col = wc*64 + j*16 + lr;
        z[rf][j][r] = acc[rf][j][r] + sold[row*M_ + col];
      }
  #pragma unroll
  for (int rf=0;rf<2;rf++)
    #pragma unroll
    for (int r=0;r<4;r++){
      float ps = 0.f, qs = 0.f;
      #pragma unroll
      for (int j=0;j<4;j++){ float t = z[rf][j][r]; ps += t; qs += t*t; }
      ps += __shfl_xor(ps,1); qs += __shfl_xor(qs,1);
      ps += __shfl_xor(ps,2); qs += __shfl_xor(qs,2);
      ps += __shfl_xor(ps,4); qs += __shfl_xor(qs,4);
      ps += __shfl_xor(ps,8); qs += __shfl_xor(qs,8);
      if (lr == 0){
        int rowl = wr*32 + rf*16 + g*4 + r;
        zs[wc][rowl][0] = ps;
        zs[wc][rowl][1] = qs;
      }
    }
  __syncthreads();
  #pragma unroll
  for (int rf=0;rf<2;rf++)
    #pragma unroll
    for (int r=0;r<4;r++){
      int rowl = wr*32 + rf*16 + g*4 + r;
      float sum = zs[0][rowl][0]+zs[1][rowl][0]+zs[2][rowl][0]+zs[3][rowl][0];
      float sq  = zs[0][rowl][1]+zs[1][rowl][1]+zs[2][rowl][1]+zs[3][rowl][1];
      float mean = sum*(1.f/M_);
      float var  = sq*(1.f/M_) - mean*mean;
      float rstd = rsqrtf(var + 1e-5f);
      int row = rowbase + rowl;
      #pragma unroll
      for (int j=0;j<4;j++){
        int col = wc*64 + j*16 + lr;
        float zv = z[rf][j][r];
        float o = (zv-mean)*rstd*lg[col] + lb[col] + zv;
        u16 hb = f2h(o);
        P1h[row*M_ + col] = hb;
        P1l[row*M_ + col] = f2h(o - h2f(hb));
      }
    }
}

// ---------------- fused MLP: gelu(smid@fc1^T+b1)@fc2^T + b2 -> out ----------------
// 64 rows/block, c-chunks of 128 FC-cols; LDS = 16+32+32 = 80KB -> 2 blocks/CU
__global__ __launch_bounds__(512) void k_fc(const u16* __restrict__ Ph, const u16* __restrict__ Pl,
    const u16* __restrict__ W1, const float* __restrict__ b1,
    const u16* __restrict__ W2, const float* __restrict__ b2, float* __restrict__ out){
  __shared__ __align__(16) u16 Abuf[64*128];   // 16KB
  __shared__ __align__(16) u16 Bbuf[256*64];   // 32KB (shared FC1/FC2)
  __shared__ __align__(16) u16 Hbuf[64*256];   // 32KB: H split, A-format, 2 kchunks
  int tid = threadIdx.x;
  int wid = tid>>6, lane = tid&63;
  int wr = wid>>2, wc = wid&3;
  int g = lane>>4, lr = lane&15;
  int rowbase = blockIdx.x*64;
  f32x4 acc2[2][4];
  #pragma unroll
  for (int rf=0;rf<2;rf++)
    #pragma unroll
    for (int j=0;j<4;j++) acc2[rf][j] = 0.f;
  for (int c=0;c<8;c++){
    f32x4 acc1[2][2];
    #pragma unroll
    for (int rf=0;rf<2;rf++)
      #pragma unroll
      for (int j=0;j<2;j++) acc1[rf][j] = 0.f;
    // ---- FC1: out cols [c*128, c*128+128), K = 256 ----
    for (int k0=0;k0<M_;k0+=64){
      #pragma unroll
      for (int it=0; it<2; it++){
        int idx = tid + it*512; int row = idx>>4, s = idx&15;
        const u16* src = (s<8 ? Ph : Pl) + (rowbase+row)*M_ + k0 + (s&7)*8;
        int ss = (s&8) | ((s ^ row) & 7);
        *(uint4*)(Abuf + row*128 + ss*8) = *(const uint4*)src;
      }
      #pragma unroll
      for (int it=0; it<2; it++){ // B1: 128 rows
        int idx = tid + it*512; int row = idx>>3, s = idx&7;
        int ss = (s ^ row) & 7;
        *(uint4*)(Bbuf + row*64 + ss*8) = *(const uint4*)(W1 + (c*128+row)*M_ + k0 + s*8);
      }
      __syncthreads();
      #pragma unroll
      for (int st=0; st<2; st++){
        f16x8 ah[2], al[2], bf[2];
        #pragma unroll
        for (int rf=0;rf<2;rf++){ int ar = wr*32 + rf*16 + lr; ah[rf]=afrag(Abuf,ar,0,st,g); al[rf]=afrag(Abuf,ar,1,st,g); }
        #pragma unroll
        for (int j=0;j<2;j++){ int br = wc*32 + j*16 + lr; bf[j]=bfrag(Bbuf,br,st,g); }
        #pragma unroll
        for (int rf=0;rf<2;rf++)
          #pragma unroll
          for (int j=0;j<2;j++){
            acc1[rf][j] = mfmah(ah[rf], bf[j], acc1[rf][j]);
            acc1[rf][j] = mfmah(al[rf], bf[j], acc1[rf][j]);
          }
      }
      __syncthreads();
    }
    // ---- gelu -> H (split, A-format with XOR swizzle) ----
    #pragma unroll
    for (int rf=0;rf<2;rf++)
      #pragma unroll
      for (int j=0;j<2;j++)
        #pragma unroll
        for (int r=0;r<4;r++){
          int rowl = wr*32 + rf*16 + g*4 + r;
          int col = wc*32 + j*16 + lr;      // 0..127 within c-chunk
          float xv = acc1[rf][j][r] + b1[c*128 + col];
          float gl = 0.5f*xv*(1.f + erff(xv*0.70710678118654752f));
          u16 hv = f2h(gl);
          u16 lv = f2h(gl - h2f(hv));
          int kc2 = col>>6, w6 = col&63;
          int sl = (w6>>3) ^ (rowl&7);
          int el = col&7;
          Hbuf[rowl*256 + kc2*128 + sl*8 + el] = hv;
          Hbuf[rowl*256 + kc2*128 + (8|sl)*8 + el] = lv;
        }
    // ---- FC2 partial: k in [c*128, c*128+128), out cols 256 ----
    for (int kcl=0;kcl<2;kcl++){
      #pragma unroll
      for (int it=0; it<4; it++){ // B2: 256 rows
        int idx = tid + it*512; int row = idx>>3, s = idx&7;
        int ss = (s ^ row) & 7;
        *(uint4*)(Bbuf + row*64 + ss*8) = *(const uint4*)(W2 + row*FF_ + c*128 + kcl*64 + s*8);
      }
      __syncthreads();   // also orders H writes before H reads
      #pragma unroll
      for (int st=0; st<2; st++){
        f16x8 ah[2], al[2], bf[4];
        #pragma unroll
        for (int rf=0;rf<2;rf++){
          int ar = wr*32 + rf*16 + lr;
          int sl = (((st<<2)|g) ^ ar) & 7;
          ah[rf] = *(const f16x8*)(Hbuf + ar*256 + kcl*128 + sl*8);
          al[rf] = *(const f16x8*)(Hbuf + ar*256 + kcl*128 + (8|sl)*8);
        }
        #pragma unroll
        for (int j=0;j<4;j++){ int br = wc*64 + j*16 + lr; bf[j]=bfrag(Bbuf,br,st,g); }
        #pragma unroll
        for (int rf=0;rf<2;rf++)
          #pragma unroll
          for (int j=0;j<4;j++){
            acc2[rf][j] = mfmah(ah[rf], bf[j], acc2[rf][j]);
            acc2[rf][j] = mfmah(al[rf], bf[j], acc2[rf][j]);
          }
      }
      __syncthreads();
    }
  }
  #pragma unroll
  for (int rf=0;rf<2;rf++)
    #pragma unroll
    for (int j=0;j<4;j++)
      #pragma unroll
      for (int r=0;r<4;r++){
        int row = rowbase + wr*32 + rf*16 + g*4 + r;
        int col = wc*64 + j*16 + lr;
        out[row*M_ + col] = acc2[rf][j][r] + b2[col];
      }
}

extern "C" void kernel_launch(void* const* d_in, const int* in_sizes, int n_in,
                              void* d_out, int out_size, void* d_ws, size_t ws_size,
                              hipStream_t stream){
  const float* x      = (const float*)d_in[0];
  const float* weight = (const float*)d_in[1];
  const float* wqkv   = (const float*)d_in[2];
  const float* wo     = (const float*)d_in[3];
  const float* ln_g   = (const float*)d_in[4];
  const float* ln_b   = (const float*)d_in[5];
  const float* lnz_g  = (const float*)d_in[6];
  const float* lnz_b  = (const float*)d_in[7];
  const float* fc1_w  = (const float*)d_in[8];
  const float* fc1_b  = (const float*)d_in[9];
  const float* fc2_w  = (const float*)d_in[10];
  const float* fc2_b  = (const float*)d_in[11];
  float* out = (float*)d_out;
  char* ws = (char*)d_ws;
  size_t off = 0;
  u16* wqkv_h = (u16*)(ws + off); off += 1572864;   // 4*768*256*2
  u16* wo_h   = (u16*)(ws + off); off += 524288;    // 4*256*256*2
  u16* fc1_h  = (u16*)(ws + off); off += 524288;
  u16* fc2_h  = (u16*)(ws + off); off += 524288;
  u16* P1h    = (u16*)(ws + off); off += 33554432;  // R*256 f16
  u16* P1l    = (u16*)(ws + off); off += 33554432;
  u16* imv    = (u16*)(ws + off); off += 33554432;
  // total 103,809,024 B
  // bias & weight_h alias P1h/P1l heads: only live before the first k_ln/k_qkv
  float* bias     = (float*)P1h;   // 512KB
  u16*   weight_h = P1l;           // 128KB

  k_bias<<<N_, M_, 0, stream>>>(bias);
  k_half<<<64, 256, 0, stream>>>(weight, weight_h, 65536/4);
  k_half_qkv<<<TK_*768, 256, 0, stream>>>(wqkv, wqkv_h);
  k_half<<<256, 256, 0, stream>>>(wo, wo_h, 262144/4);
  k_half<<<256, 256, 0, stream>>>(fc1_w, fc1_h, 262144/4);
  k_half<<<256, 256, 0, stream>>>(fc2_w, fc2_h, 262144/4);
  k_init<<<R_/64, 512, 0, stream>>>(x, weight_h, bias, out);
  for (int a=0; a<TK_; a++){
    k_ln<<<R_/16, 256, 0, stream>>>(out, ln_g, ln_b, P1h, P1l);
    k_qkv<<<dim3(R_/64, 2), 512, 0, stream>>>(P1h, P1l, wqkv_h + a*768*M_, imv);
    k_scan<<<L_, 256, 0, stream>>>(imv, P1h, P1l);
    k_wo<<<R_/64, 512, 0, stream>>>(P1h, P1l, wo_h + a*65536, out, lnz_g, lnz_b);
    k_fc<<<R_/64, 512, 0, stream>>>(P1h, P1l, fc1_h, fc1_b, fc2_h, fc2_b, out);
  }
}

// Round 6
// 1188.159 us; speedup vs baseline: 3.5620x; 1.4295x over previous
//
#include <hip/hip_runtime.h>

typedef unsigned int u32;
typedef unsigned short u16;
typedef _Float16 f16;
typedef __attribute__((ext_vector_type(8))) _Float16 f16x8;
typedef __attribute__((ext_vector_type(4))) float f32x4;
typedef __attribute__((ext_vector_type(4))) u16 u16x4;

#define L_ 128
#define N_ 512
#define M_ 256
#define TK_ 4
#define H_ 8
#define R_ (L_*N_)
#define FF_ 1024

__device__ __forceinline__ u16 f2h(float v){ f16 h=(f16)v; return __builtin_bit_cast(u16,h); }
__device__ __forceinline__ float h2f(u16 b){ return (float)__builtin_bit_cast(f16,b); }
__device__ __forceinline__ f32x4 mfmah(f16x8 a, f16x8 b, f32x4 c){
  return __builtin_amdgcn_mfma_f32_16x16x32_f16(a,b,c,0,0,0);
}
// LDS tile: [row][8 slots of 8 f16], row stride 64 u16 (128B), slot XOR-swizzled by row&7.
__device__ __forceinline__ f16x8 frag(const u16* buf, int row, int st, int g){
  int sl = (((st<<2)|g) ^ row) & 7;
  return *(const f16x8*)(buf + row*64 + sl*8);
}

// ---------------- prep ----------------
__global__ void k_bias(float* __restrict__ bias){
  int j = blockIdx.x, l = threadIdx.x;
  int t = l>>1;
  float base = expf(-0.14391156831212757f * (float)t); // ln(10000)/64
  float ang = (float)j * base;
  bias[j*M_ + l] = (l&1) ? cosf(ang) : sinf(ang);
}

__global__ void k_half(const float* __restrict__ src, u16* __restrict__ dst, int n4){
  int i = blockIdx.x*256 + threadIdx.x;
  if (i < n4){
    float4 v = ((const float4*)src)[i];
    u16x4 o;
    o[0]=f2h(v.x); o[1]=f2h(v.y); o[2]=f2h(v.z); o[3]=f2h(v.w);
    *(u16x4*)(dst + i*4) = o;
  }
}

// Wqkv[a,x,hd,d,m] -> f16 [a][hd*96 + x*32 + d][m]
__global__ void k_half_qkv(const float* __restrict__ w, u16* __restrict__ dst){
  int b = blockIdx.x, m = threadIdx.x;
  int a = b/768, colp = b%768;
  int hd = colp/96, rem = colp%96, x = rem/32, d = rem&31;
  dst[b*M_ + m] = f2h(w[(((a*3 + x)*H_ + hd)*32 + d)*M_ + m]);
}

// ---------------- k_init: out = x @ weight^T + bias ----------------
__global__ __launch_bounds__(512) void k_init(const float* __restrict__ X, const u16* __restrict__ Wh,
    const float* __restrict__ bias, float* __restrict__ out){
  __shared__ __align__(16) u16 Abuf[128*64];
  __shared__ __align__(16) u16 Bbuf[256*64];
  int tid = threadIdx.x;
  int wid = tid>>6, lane = tid&63;
  int wy = wid>>2, wx = wid&3;
  int g = lane>>4, lr = lane&15;
  int rowbase = blockIdx.x*128;
  f32x4 acc[4][4];
  #pragma unroll
  for (int i=0;i<4;i++)
    #pragma unroll
    for (int j=0;j<4;j++) acc[i][j] = 0.f;
  for (int k0=0;k0<M_;k0+=64){
    #pragma unroll
    for (int it=0; it<2; it++){ // A: 128 rows x 8 slots, f32->f16
      int idx = tid + it*512; int row = idx>>3, s = idx&7;
      const float* sp = X + (rowbase+row)*M_ + k0 + s*8;
      float4 v0 = *(const float4*)sp, v1 = *(const float4*)(sp+4);
      float vv[8] = {v0.x,v0.y,v0.z,v0.w,v1.x,v1.y,v1.z,v1.w};
      f16x8 hv;
      #pragma unroll
      for (int e=0;e<8;e++) hv[e] = (f16)vv[e];
      *(f16x8*)(Abuf + row*64 + ((s^row)&7)*8) = hv;
    }
    #pragma unroll
    for (int it=0; it<4; it++){ // B: 256 rows x 8 slots
      int idx = tid + it*512; int row = idx>>3, s = idx&7;
      *(uint4*)(Bbuf + row*64 + ((s^row)&7)*8) = *(const uint4*)(Wh + row*M_ + k0 + s*8);
    }
    __syncthreads();
    #pragma unroll
    for (int st=0; st<2; st++){
      f16x8 a[4], b[4];
      #pragma unroll
      for (int i=0;i<4;i++) a[i] = frag(Abuf, wy*64 + i*16 + lr, st, g);
      #pragma unroll
      for (int j=0;j<4;j++) b[j] = frag(Bbuf, wx*64 + j*16 + lr, st, g);
      #pragma unroll
      for (int i=0;i<4;i++)
        #pragma unroll
        for (int j=0;j<4;j++) acc[i][j] = mfmah(a[i], b[j], acc[i][j]);
    }
    __syncthreads();
  }
  #pragma unroll
  for (int i=0;i<4;i++)
    #pragma unroll
    for (int j=0;j<4;j++)
      #pragma unroll
      for (int r=0;r<4;r++){
        int row = rowbase + wy*64 + i*16 + g*4 + r;
        int col = wx*64 + j*16 + lr;
        out[row*M_ + col] = acc[i][j][r] + bias[(row & (N_-1))*M_ + col];
      }
}

// ---------------- LN(s) -> f16 plane ----------------
__global__ __launch_bounds__(256) void k_ln(const float* __restrict__ s, const float* __restrict__ lg,
    const float* __restrict__ lb, u16* __restrict__ P1){
  int tid = threadIdx.x;
  int rl = tid>>4, c16 = tid&15;
  int row = blockIdx.x*16 + rl;
  const float* sr = s + row*M_ + c16*16;
  float v[16];
  #pragma unroll
  for (int q=0;q<4;q++){
    float4 t = ((const float4*)sr)[q];
    v[q*4+0]=t.x; v[q*4+1]=t.y; v[q*4+2]=t.z; v[q*4+3]=t.w;
  }
  float sum=0.f, sq=0.f;
  #pragma unroll
  for (int e=0;e<16;e++){ sum+=v[e]; sq+=v[e]*v[e]; }
  #pragma unroll
  for (int o=1;o<16;o<<=1){ sum += __shfl_xor(sum,o); sq += __shfl_xor(sq,o); }
  float mean = sum*(1.f/M_);
  float var  = sq*(1.f/M_) - mean*mean;
  float rstd = rsqrtf(var + 1e-5f);
  #pragma unroll
  for (int q=0;q<4;q++){
    int col = c16*16 + q*4;
    u16x4 hv;
    #pragma unroll
    for (int e=0;e<4;e++){
      float o = (v[q*4+e]-mean)*rstd*lg[col+e] + lb[col+e];
      hv[e] = f2h(o);
    }
    *(u16x4*)(P1 + row*M_ + col) = hv;
  }
}

// ---------------- QKV GEMM + fused rsa -> imv(f16) ----------------
// grid (R/128, 2); 128 rows/block, 4 heads/block; wave = (head, row-half of 64)
__global__ __launch_bounds__(512) void k_qkv(const u16* __restrict__ P1, const u16* __restrict__ Wq,
    u16* __restrict__ imv){
  __shared__ __align__(16) u16 Abuf[128*64];
  __shared__ __align__(16) u16 Bbuf[384*64];
  int tid = threadIdx.x;
  int wid = tid>>6, lane = tid&63;
  int hd = wid>>1, sub = wid&1;
  int g = lane>>4, lr = lane&15;
  int rowbase = blockIdx.x*128;
  int hbase = blockIdx.y*384;
  f32x4 acc[4][6];
  #pragma unroll
  for (int i=0;i<4;i++)
    #pragma unroll
    for (int c=0;c<6;c++) acc[i][c] = 0.f;
  for (int k0=0;k0<M_;k0+=64){
    #pragma unroll
    for (int it=0; it<2; it++){ // A: 128 rows
      int idx = tid + it*512; int row = idx>>3, s = idx&7;
      *(uint4*)(Abuf + row*64 + ((s^row)&7)*8) = *(const uint4*)(P1 + (rowbase+row)*M_ + k0 + s*8);
    }
    #pragma unroll
    for (int it=0; it<6; it++){ // B: 384 rows
      int idx = tid + it*512; int row = idx>>3, s = idx&7;
      *(uint4*)(Bbuf + row*64 + ((s^row)&7)*8) = *(const uint4*)(Wq + (hbase+row)*M_ + k0 + s*8);
    }
    __syncthreads();
    #pragma unroll
    for (int st=0; st<2; st++){
      f16x8 a[4];
      #pragma unroll
      for (int i=0;i<4;i++) a[i] = frag(Abuf, sub*64 + i*16 + lr, st, g);
      #pragma unroll
      for (int c=0;c<6;c++){
        f16x8 b = frag(Bbuf, hd*96 + c*16 + lr, st, g);
        #pragma unroll
        for (int i=0;i<4;i++) acc[i][c] = mfmah(a[i], b, acc[i][c]);
      }
    }
    __syncthreads();
  }
  const float isd = 0.17677669529663687f; // 1/sqrt(32)
  int head = blockIdx.y*4 + hd;
  #pragma unroll
  for (int i=0;i<4;i++){
    f32x4 p = acc[i][0]*acc[i][2] + acc[i][1]*acc[i][3];
    #pragma unroll
    for (int r=0;r<4;r++){
      float v = p[r];
      v += __shfl_xor(v,1); v += __shfl_xor(v,2);
      v += __shfl_xor(v,4); v += __shfl_xor(v,8);
      float rsa = v * isd;
      int row = rowbase + sub*64 + i*16 + g*4 + r;
      imv[row*M_ + head*32 + lr]      = f2h(rsa*acc[i][4][r]);
      imv[row*M_ + head*32 + 16 + lr] = f2h(rsa*acc[i][5][r]);
    }
  }
}

// ---------------- cumsum over j: imv(f16) -> P1(f16) ----------------
__global__ void k_scan(const u16* __restrict__ imv, u16* __restrict__ P1){
  int i = blockIdx.x, m = threadIdx.x;
  int base = i*N_*M_ + m;
  float acc = 0.f;
  for (int jb=0; jb<N_; jb+=8){
    float t[8];
    #pragma unroll
    for (int u=0;u<8;u++) t[u] = h2f(imv[base + (jb+u)*M_]);
    #pragma unroll
    for (int u=0;u<8;u++){
      acc += t[u];
      P1[base + (jb+u)*M_] = f2h(acc);
    }
  }
}

// ---------------- Wo GEMM + s_old + LN + residual -> P1(f16, in-place) ----------------
__global__ __launch_bounds__(512) void k_wo(u16* __restrict__ P1, const u16* __restrict__ Wh,
    const float* __restrict__ sold, const float* __restrict__ lg, const float* __restrict__ lb){
  __shared__ __align__(16) u16 Abuf[128*64];
  __shared__ __align__(16) u16 Bbuf[256*64];
  __shared__ float zs[4][128][2];
  int tid = threadIdx.x;
  int wid = tid>>6, lane = tid&63;
  int wy = wid>>2, wx = wid&3;
  int g = lane>>4, lr = lane&15;
  int rowbase = blockIdx.x*128;
  f32x4 acc[4][4];
  #pragma unroll
  for (int i=0;i<4;i++)
    #pragma unroll
    for (int j=0;j<4;j++) acc[i][j] = 0.f;
  for (int k0=0;k0<M_;k0+=64){
    #pragma unroll
    for (int it=0; it<2; it++){
      int idx = tid + it*512; int row = idx>>3, s = idx&7;
      *(uint4*)(Abuf + row*64 + ((s^row)&7)*8) = *(const uint4*)(P1 + (rowbase+row)*M_ + k0 + s*8);
    }
    #pragma unroll
    for (int it=0; it<4; it++){
      int idx = tid + it*512; int row = idx>>3, s = idx&7;
      *(uint4*)(Bbuf + row*64 + ((s^row)&7)*8) = *(const uint4*)(Wh + row*M_ + k0 + s*8);
    }
    __syncthreads();
    #pragma unroll
    for (int st=0; st<2; st++){
      f16x8 a[4], b[4];
      #pragma unroll
      for (int i=0;i<4;i++) a[i] = frag(Abuf, wy*64 + i*16 + lr, st, g);
      #pragma unroll
      for (int j=0;j<4;j++) b[j] = frag(Bbuf, wx*64 + j*16 + lr, st, g);
      #pragma unroll
      for (int i=0;i<4;i++)
        #pragma unroll
        for (int j=0;j<4;j++) acc[i][j] = mfmah(a[i], b[j], acc[i][j]);
    }
    __syncthreads();
  }
  // z = acc + sold (in-place into acc)
  #pragma unroll
  for (int i=0;i<4;i++)
    #pragma unroll
    for (int j=0;j<4;j++)
      #pragma unroll
      for (int r=0;r<4;r++){
        int row = rowbase + wy*64 + i*16 + g*4 + r;
        int col = wx*64 + j*16 + lr;
        acc[i][j][r] += sold[row*M_ + col];
      }
  #pragma unroll
  for (int i=0;i<4;i++)
    #pragma unroll
    for (int r=0;r<4;r++){
      float ps = 0.f, qs = 0.f;
      #pragma unroll
      for (int j=0;j<4;j++){ float t = acc[i][j][r]; ps += t; qs += t*t; }
      ps += __shfl_xor(ps,1); qs += __shfl_xor(qs,1);
      ps += __shfl_xor(ps,2); qs += __shfl_xor(qs,2);
      ps += __shfl_xor(ps,4); qs += __shfl_xor(qs,4);
      ps += __shfl_xor(ps,8); qs += __shfl_xor(qs,8);
      if (lr == 0){
        int rowl = wy*64 + i*16 + g*4 + r;
        zs[wx][rowl][0] = ps;
        zs[wx][rowl][1] = qs;
      }
    }
  __syncthreads();
  #pragma unroll
  for (int i=0;i<4;i++)
    #pragma unroll
    for (int r=0;r<4;r++){
      int rowl = wy*64 + i*16 + g*4 + r;
      float sum = zs[0][rowl][0]+zs[1][rowl][0]+zs[2][rowl][0]+zs[3][rowl][0];
      float sq  = zs[0][rowl][1]+zs[1][rowl][1]+zs[2][rowl][1]+zs[3][rowl][1];
      float mean = sum*(1.f/M_);
      float var  = sq*(1.f/M_) - mean*mean;
      float rstd = rsqrtf(var + 1e-5f);
      int row = rowbase + rowl;
      #pragma unroll
      for (int j=0;j<4;j++){
        int col = wx*64 + j*16 + lr;
        float zv = acc[i][j][r];
        float o = (zv-mean)*rstd*lg[col] + lb[col] + zv;
        P1[row*M_ + col] = f2h(o);
      }
    }
}

// ---------------- fused MLP: gelu(smid@fc1^T+b1)@fc2^T + b2 -> out ----------------
// 128 rows/block, c-chunks of 256 FC-cols. FC1 computed TRANSPOSED: mfma(W1frag, smidfrag)
// so each lane holds 4 consecutive H-cols of one row -> u16x4 H stores.
__global__ __launch_bounds__(512) void k_fc(const u16* __restrict__ P1,
    const u16* __restrict__ W1, const float* __restrict__ b1,
    const u16* __restrict__ W2, const float* __restrict__ b2, float* __restrict__ out){
  __shared__ __align__(16) u16 Abuf[128*64];   // 16KB: smid tile
  __shared__ __align__(16) u16 Bbuf[256*64];   // 32KB: W1 / W2 tiles
  __shared__ __align__(16) u16 Hbuf[128*256];  // 64KB: H, A-fragment format, 4 kchunks
  int tid = threadIdx.x;
  int wid = tid>>6, lane = tid&63;
  int wy = wid>>2, wx = wid&3;   // wy: row-half (64 rows) / fcol use; wx: col group
  int g = lane>>4, lr = lane&15;
  int rowbase = blockIdx.x*128;
  f32x4 acc2[4][4];
  #pragma unroll
  for (int i=0;i<4;i++)
    #pragma unroll
    for (int j=0;j<4;j++) acc2[i][j] = 0.f;
  for (int c=0;c<4;c++){
    f32x4 acc1[4][4];   // [fcol frag i][smidrow frag jj], transposed C
    #pragma unroll
    for (int i=0;i<4;i++)
      #pragma unroll
      for (int j=0;j<4;j++) acc1[i][j] = 0.f;
    // ---- FC1 (transposed): fcols [c*256, c*256+256), K = 256 ----
    for (int k0=0;k0<M_;k0+=64){
      #pragma unroll
      for (int it=0; it<2; it++){ // A: smid 128 rows
        int idx = tid + it*512; int row = idx>>3, s = idx&7;
        *(uint4*)(Abuf + row*64 + ((s^row)&7)*8) = *(const uint4*)(P1 + (rowbase+row)*M_ + k0 + s*8);
      }
      #pragma unroll
      for (int it=0; it<4; it++){ // B: W1, 256 fcol-rows
        int idx = tid + it*512; int row = idx>>3, s = idx&7;
        *(uint4*)(Bbuf + row*64 + ((s^row)&7)*8) = *(const uint4*)(W1 + (c*256+row)*M_ + k0 + s*8);
      }
      __syncthreads();
      #pragma unroll
      for (int st=0; st<2; st++){
        f16x8 aw[4], bs[4];
        #pragma unroll
        for (int i=0;i<4;i++) aw[i] = frag(Bbuf, wx*64 + i*16 + lr, st, g);   // W1 frags
        #pragma unroll
        for (int j=0;j<4;j++) bs[j] = frag(Abuf, wy*64 + j*16 + lr, st, g);   // smid frags
        #pragma unroll
        for (int i=0;i<4;i++)
          #pragma unroll
          for (int j=0;j<4;j++) acc1[i][j] = mfmah(aw[i], bs[j], acc1[i][j]);
      }
      __syncthreads();
    }
    // ---- gelu -> Hbuf (A-format, swizzled); lane holds 4 consecutive fcols of one row ----
    #pragma unroll
    for (int i=0;i<4;i++){
      int fbase = wx*64 + i*16 + g*4;           // fcol local (0..255), +r
      int klocal = fbase & 63;                   // i*16 + g*4
      int kc = fbase >> 6;                       // == wx
      #pragma unroll
      for (int j=0;j<4;j++){
        int smrow = wy*64 + j*16 + lr;
        u16x4 hv;
        #pragma unroll
        for (int r=0;r<4;r++){
          float xv = acc1[i][j][r] + b1[c*256 + fbase + r];
          float gl = 0.5f*xv*(1.f + erff(xv*0.70710678118654752f));
          hv[r] = f2h(gl);
        }
        int phys = ((klocal>>3) ^ smrow) & 7;
        *(u16x4*)(Hbuf + smrow*256 + kc*64 + phys*8 + (klocal&7)) = hv;
      }
    }
    // ---- FC2 partial: k in [c*256, c*256+256), 256 out cols ----
    for (int kcl=0;kcl<4;kcl++){
      #pragma unroll
      for (int it=0; it<4; it++){ // B: W2, 256 out-rows
        int idx = tid + it*512; int row = idx>>3, s = idx&7;
        *(uint4*)(Bbuf + row*64 + ((s^row)&7)*8) = *(const uint4*)(W2 + row*FF_ + c*256 + kcl*64 + s*8);
      }
      __syncthreads();   // orders H writes before H reads too
      #pragma unroll
      for (int st=0; st<2; st++){
        f16x8 ah[4], b[4];
        #pragma unroll
        for (int i=0;i<4;i++){
          int hrow = wy*64 + i*16 + lr;
          int phys = ((((st<<2)|g)) ^ hrow) & 7;
          ah[i] = *(const f16x8*)(Hbuf + hrow*256 + kcl*64 + phys*8);
        }
        #pragma unroll
        for (int j=0;j<4;j++) b[j] = frag(Bbuf, wx*64 + j*16 + lr, st, g);
        #pragma unroll
        for (int i=0;i<4;i++)
          #pragma unroll
          for (int j=0;j<4;j++) acc2[i][j] = mfmah(ah[i], b[j], acc2[i][j]);
      }
      __syncthreads();
    }
  }
  #pragma unroll
  for (int i=0;i<4;i++)
    #pragma unroll
    for (int j=0;j<4;j++)
      #pragma unroll
      for (int r=0;r<4;r++){
        int row = rowbase + wy*64 + i*16 + g*4 + r;
        int col = wx*64 + j*16 + lr;
        out[row*M_ + col] = acc2[i][j][r] + b2[col];
      }
}

extern "C" void kernel_launch(void* const* d_in, const int* in_sizes, int n_in,
                              void* d_out, int out_size, void* d_ws, size_t ws_size,
                              hipStream_t stream){
  const float* x      = (const float*)d_in[0];
  const float* weight = (const float*)d_in[1];
  const float* wqkv   = (const float*)d_in[2];
  const float* wo     = (const float*)d_in[3];
  const float* ln_g   = (const float*)d_in[4];
  const float* ln_b   = (const float*)d_in[5];
  const float* lnz_g  = (const float*)d_in[6];
  const float* lnz_b  = (const float*)d_in[7];
  const float* fc1_w  = (const float*)d_in[8];
  const float* fc1_b  = (const float*)d_in[9];
  const float* fc2_w  = (const float*)d_in[10];
  const float* fc2_b  = (const float*)d_in[11];
  float* out = (float*)d_out;
  char* ws = (char*)d_ws;
  size_t off = 0;
  u16* wqkv_h = (u16*)(ws + off); off += 1572864;   // 4*768*256*2
  u16* wo_h   = (u16*)(ws + off); off += 524288;
  u16* fc1_h  = (u16*)(ws + off); off += 524288;
  u16* fc2_h  = (u16*)(ws + off); off += 524288;
  u16* P1     = (u16*)(ws + off); off += 33554432;  // R*256 f16 (LN-out -> cumsum -> smid)
  u16* imv    = (u16*)(ws + off); off += 33554432;  // R*256 f16 pre-scan imv
  // bias(f32 512KB) + weight_h(128KB) alias imv head: dead before k_qkv writes imv
  float* bias     = (float*)imv;
  u16*   weight_h = (u16*)((char*)imv + 524288);

  k_bias<<<N_, M_, 0, stream>>>(bias);
  k_half<<<64, 256, 0, stream>>>(weight, weight_h, 65536/4);
  k_half_qkv<<<TK_*768, 256, 0, stream>>>(wqkv, wqkv_h);
  k_half<<<256, 256, 0, stream>>>(wo, wo_h, 262144/4);
  k_half<<<256, 256, 0, stream>>>(fc1_w, fc1_h, 262144/4);
  k_half<<<256, 256, 0, stream>>>(fc2_w, fc2_h, 262144/4);
  k_init<<<R_/128, 512, 0, stream>>>(x, weight_h, bias, out);
  for (int a=0; a<TK_; a++){
    k_ln<<<R_/16, 256, 0, stream>>>(out, ln_g, ln_b, P1);
    k_qkv<<<dim3(R_/128, 2), 512, 0, stream>>>(P1, wqkv_h + a*768*M_, imv);
    k_scan<<<L_, 256, 0, stream>>>(imv, P1);
    k_wo<<<R_/128, 512, 0, stream>>>(P1, wo_h + a*65536, out, lnz_g, lnz_b);
    k_fc<<<R_/128, 512, 0, stream>>>(P1, fc1_h, fc1_b, fc2_h, fc2_b, out);
  }
}

// Round 7
// 1060.302 us; speedup vs baseline: 3.9915x; 1.1206x over previous
//
#include <hip/hip_runtime.h>

typedef unsigned int u32;
typedef unsigned short u16;
typedef _Float16 f16;
typedef __attribute__((ext_vector_type(8))) _Float16 f16x8;
typedef __attribute__((ext_vector_type(4))) float f32x4;
typedef __attribute__((ext_vector_type(4))) u16 u16x4;

#define L_ 128
#define N_ 512
#define M_ 256
#define TK_ 4
#define H_ 8
#define R_ (L_*N_)
#define FF_ 1024

__device__ __forceinline__ u16 f2h(float v){ f16 h=(f16)v; return __builtin_bit_cast(u16,h); }
__device__ __forceinline__ float h2f(u16 b){ return (float)__builtin_bit_cast(f16,b); }
__device__ __forceinline__ f32x4 mfmah(f16x8 a, f16x8 b, f32x4 c){
  return __builtin_amdgcn_mfma_f32_16x16x32_f16(a,b,c,0,0,0);
}
// LDS tile: [row][8 slots of 8 f16], row stride 64 u16 (128B), slot XOR-swizzled by row&7.
__device__ __forceinline__ f16x8 frag(const u16* buf, int row, int st, int g){
  int sl = (((st<<2)|g) ^ row) & 7;
  return *(const f16x8*)(buf + row*64 + sl*8);
}
// tanh-form gelu: x*(1 - 1/(exp(2u)+1)), u = x*(c1 + c2*x^2). max err vs erf-gelu ~3e-4
__device__ __forceinline__ float gelu_f(float x){
  float u = x*(0.7978845608f + 0.0356774081f*x*x);
  float e = __expf(u + u);
  float r = __builtin_amdgcn_rcpf(e + 1.f);
  return x - x*r;
}

// ---------------- prep ----------------
__global__ void k_bias(float* __restrict__ bias){
  int j = blockIdx.x, l = threadIdx.x;
  int t = l>>1;
  float base = expf(-0.14391156831212757f * (float)t); // ln(10000)/64
  float ang = (float)j * base;
  bias[j*M_ + l] = (l&1) ? cosf(ang) : sinf(ang);
}

__global__ void k_half(const float* __restrict__ src, u16* __restrict__ dst, int n4){
  int i = blockIdx.x*256 + threadIdx.x;
  if (i < n4){
    float4 v = ((const float4*)src)[i];
    u16x4 o;
    o[0]=f2h(v.x); o[1]=f2h(v.y); o[2]=f2h(v.z); o[3]=f2h(v.w);
    *(u16x4*)(dst + i*4) = o;
  }
}

// Wqkv[a,x,hd,d,m] -> f16 [a][hd*96 + x*32 + d][m]
__global__ void k_half_qkv(const float* __restrict__ w, u16* __restrict__ dst){
  int b = blockIdx.x, m = threadIdx.x;
  int a = b/768, colp = b%768;
  int hd = colp/96, rem = colp%96, x = rem/32, d = rem&31;
  dst[b*M_ + m] = f2h(w[(((a*3 + x)*H_ + hd)*32 + d)*M_ + m]);
}

// ---------------- k_init: z = x @ weight^T + bias; out=z, P1=f16(LN(z)) ----------------
__global__ __launch_bounds__(512) void k_init(const float* __restrict__ X, const u16* __restrict__ Wh,
    const float* __restrict__ bias, const float* __restrict__ lg, const float* __restrict__ lb,
    float* __restrict__ out, u16* __restrict__ P1){
  __shared__ __align__(16) u16 Abuf[128*64];
  __shared__ __align__(16) u16 Bbuf[256*64];
  __shared__ float zs[4][128][2];
  int tid = threadIdx.x;
  int wid = tid>>6, lane = tid&63;
  int wy = wid>>2, wx = wid&3;
  int g = lane>>4, lr = lane&15;
  int rowbase = blockIdx.x*128;
  f32x4 acc[4][4];
  #pragma unroll
  for (int i=0;i<4;i++)
    #pragma unroll
    for (int j=0;j<4;j++) acc[i][j] = 0.f;
  for (int k0=0;k0<M_;k0+=64){
    #pragma unroll
    for (int it=0; it<2; it++){ // A: 128 rows x 8 slots, f32->f16
      int idx = tid + it*512; int row = idx>>3, s = idx&7;
      const float* sp = X + (rowbase+row)*M_ + k0 + s*8;
      float4 v0 = *(const float4*)sp, v1 = *(const float4*)(sp+4);
      float vv[8] = {v0.x,v0.y,v0.z,v0.w,v1.x,v1.y,v1.z,v1.w};
      f16x8 hv;
      #pragma unroll
      for (int e=0;e<8;e++) hv[e] = (f16)vv[e];
      *(f16x8*)(Abuf + row*64 + ((s^row)&7)*8) = hv;
    }
    #pragma unroll
    for (int it=0; it<4; it++){ // B: 256 rows x 8 slots
      int idx = tid + it*512; int row = idx>>3, s = idx&7;
      *(uint4*)(Bbuf + row*64 + ((s^row)&7)*8) = *(const uint4*)(Wh + row*M_ + k0 + s*8);
    }
    __syncthreads();
    #pragma unroll
    for (int st=0; st<2; st++){
      f16x8 a[4], b[4];
      #pragma unroll
      for (int i=0;i<4;i++) a[i] = frag(Abuf, wy*64 + i*16 + lr, st, g);
      #pragma unroll
      for (int j=0;j<4;j++) b[j] = frag(Bbuf, wx*64 + j*16 + lr, st, g);
      #pragma unroll
      for (int i=0;i<4;i++)
        #pragma unroll
        for (int j=0;j<4;j++) acc[i][j] = mfmah(a[i], b[j], acc[i][j]);
    }
    __syncthreads();
  }
  // z = acc + bias -> out; LN epilogue -> P1
  #pragma unroll
  for (int i=0;i<4;i++)
    #pragma unroll
    for (int j=0;j<4;j++)
      #pragma unroll
      for (int r=0;r<4;r++){
        int row = rowbase + wy*64 + i*16 + g*4 + r;
        int col = wx*64 + j*16 + lr;
        acc[i][j][r] += bias[(row & (N_-1))*M_ + col];
        out[row*M_ + col] = acc[i][j][r];
      }
  #pragma unroll
  for (int i=0;i<4;i++)
    #pragma unroll
    for (int r=0;r<4;r++){
      float ps = 0.f, qs = 0.f;
      #pragma unroll
      for (int j=0;j<4;j++){ float t = acc[i][j][r]; ps += t; qs += t*t; }
      ps += __shfl_xor(ps,1); qs += __shfl_xor(qs,1);
      ps += __shfl_xor(ps,2); qs += __shfl_xor(qs,2);
      ps += __shfl_xor(ps,4); qs += __shfl_xor(qs,4);
      ps += __shfl_xor(ps,8); qs += __shfl_xor(qs,8);
      if (lr == 0){
        int rowl = wy*64 + i*16 + g*4 + r;
        zs[wx][rowl][0] = ps;
        zs[wx][rowl][1] = qs;
      }
    }
  __syncthreads();
  #pragma unroll
  for (int i=0;i<4;i++)
    #pragma unroll
    for (int r=0;r<4;r++){
      int rowl = wy*64 + i*16 + g*4 + r;
      float sum = zs[0][rowl][0]+zs[1][rowl][0]+zs[2][rowl][0]+zs[3][rowl][0];
      float sq  = zs[0][rowl][1]+zs[1][rowl][1]+zs[2][rowl][1]+zs[3][rowl][1];
      float mean = sum*(1.f/M_);
      float var  = sq*(1.f/M_) - mean*mean;
      float rstd = rsqrtf(var + 1e-5f);
      int row = rowbase + rowl;
      #pragma unroll
      for (int j=0;j<4;j++){
        int col = wx*64 + j*16 + lr;
        P1[row*M_ + col] = f2h((acc[i][j][r]-mean)*rstd*lg[col] + lb[col]);
      }
    }
}

// ---------------- QKV GEMM + fused rsa -> imv(f16) ----------------
__global__ __launch_bounds__(512) void k_qkv(const u16* __restrict__ P1, const u16* __restrict__ Wq,
    u16* __restrict__ imv){
  __shared__ __align__(16) u16 Abuf[128*64];
  __shared__ __align__(16) u16 Bbuf[384*64];
  int tid = threadIdx.x;
  int wid = tid>>6, lane = tid&63;
  int hd = wid>>1, sub = wid&1;
  int g = lane>>4, lr = lane&15;
  int rowbase = blockIdx.x*128;
  int hbase = blockIdx.y*384;
  f32x4 acc[4][6];
  #pragma unroll
  for (int i=0;i<4;i++)
    #pragma unroll
    for (int c=0;c<6;c++) acc[i][c] = 0.f;
  for (int k0=0;k0<M_;k0+=64){
    #pragma unroll
    for (int it=0; it<2; it++){ // A: 128 rows
      int idx = tid + it*512; int row = idx>>3, s = idx&7;
      *(uint4*)(Abuf + row*64 + ((s^row)&7)*8) = *(const uint4*)(P1 + (rowbase+row)*M_ + k0 + s*8);
    }
    #pragma unroll
    for (int it=0; it<6; it++){ // B: 384 rows
      int idx = tid + it*512; int row = idx>>3, s = idx&7;
      *(uint4*)(Bbuf + row*64 + ((s^row)&7)*8) = *(const uint4*)(Wq + (hbase+row)*M_ + k0 + s*8);
    }
    __syncthreads();
    #pragma unroll
    for (int st=0; st<2; st++){
      f16x8 a[4];
      #pragma unroll
      for (int i=0;i<4;i++) a[i] = frag(Abuf, sub*64 + i*16 + lr, st, g);
      #pragma unroll
      for (int c=0;c<6;c++){
        f16x8 b = frag(Bbuf, hd*96 + c*16 + lr, st, g);
        #pragma unroll
        for (int i=0;i<4;i++) acc[i][c] = mfmah(a[i], b, acc[i][c]);
      }
    }
    __syncthreads();
  }
  const float isd = 0.17677669529663687f; // 1/sqrt(32)
  int head = blockIdx.y*4 + hd;
  #pragma unroll
  for (int i=0;i<4;i++){
    f32x4 p = acc[i][0]*acc[i][2] + acc[i][1]*acc[i][3];
    #pragma unroll
    for (int r=0;r<4;r++){
      float v = p[r];
      v += __shfl_xor(v,1); v += __shfl_xor(v,2);
      v += __shfl_xor(v,4); v += __shfl_xor(v,8);
      float rsa = v * isd;
      int row = rowbase + sub*64 + i*16 + g*4 + r;
      imv[row*M_ + head*32 + lr]      = f2h(rsa*acc[i][4][r]);
      imv[row*M_ + head*32 + 16 + lr] = f2h(rsa*acc[i][5][r]);
    }
  }
}

// ---------------- cumsum over j: imv(f16) -> P1(f16) ----------------
__global__ void k_scan(const u16* __restrict__ imv, u16* __restrict__ P1){
  int i = blockIdx.x, m = threadIdx.x;
  int base = i*N_*M_ + m;
  float acc = 0.f;
  for (int jb=0; jb<N_; jb+=8){
    float t[8];
    #pragma unroll
    for (int u=0;u<8;u++) t[u] = h2f(imv[base + (jb+u)*M_]);
    #pragma unroll
    for (int u=0;u<8;u++){
      acc += t[u];
      P1[base + (jb+u)*M_] = f2h(acc);
    }
  }
}

// ---------------- Wo GEMM + s_old + LN + residual -> P1(f16, in-place) ----------------
__global__ __launch_bounds__(512) void k_wo(u16* __restrict__ P1, const u16* __restrict__ Wh,
    const float* __restrict__ sold, const float* __restrict__ lg, const float* __restrict__ lb){
  __shared__ __align__(16) u16 Abuf[128*64];
  __shared__ __align__(16) u16 Bbuf[256*64];
  __shared__ float zs[4][128][2];
  int tid = threadIdx.x;
  int wid = tid>>6, lane = tid&63;
  int wy = wid>>2, wx = wid&3;
  int g = lane>>4, lr = lane&15;
  int rowbase = blockIdx.x*128;
  f32x4 acc[4][4];
  #pragma unroll
  for (int i=0;i<4;i++)
    #pragma unroll
    for (int j=0;j<4;j++) acc[i][j] = 0.f;
  for (int k0=0;k0<M_;k0+=64){
    #pragma unroll
    for (int it=0; it<2; it++){
      int idx = tid + it*512; int row = idx>>3, s = idx&7;
      *(uint4*)(Abuf + row*64 + ((s^row)&7)*8) = *(const uint4*)(P1 + (rowbase+row)*M_ + k0 + s*8);
    }
    #pragma unroll
    for (int it=0; it<4; it++){
      int idx = tid + it*512; int row = idx>>3, s = idx&7;
      *(uint4*)(Bbuf + row*64 + ((s^row)&7)*8) = *(const uint4*)(Wh + row*M_ + k0 + s*8);
    }
    __syncthreads();
    #pragma unroll
    for (int st=0; st<2; st++){
      f16x8 a[4], b[4];
      #pragma unroll
      for (int i=0;i<4;i++) a[i] = frag(Abuf, wy*64 + i*16 + lr, st, g);
      #pragma unroll
      for (int j=0;j<4;j++) b[j] = frag(Bbuf, wx*64 + j*16 + lr, st, g);
      #pragma unroll
      for (int i=0;i<4;i++)
        #pragma unroll
        for (int j=0;j<4;j++) acc[i][j] = mfmah(a[i], b[j], acc[i][j]);
    }
    __syncthreads();
  }
  #pragma unroll
  for (int i=0;i<4;i++)
    #pragma unroll
    for (int j=0;j<4;j++)
      #pragma unroll
      for (int r=0;r<4;r++){
        int row = rowbase + wy*64 + i*16 + g*4 + r;
        int col = wx*64 + j*16 + lr;
        acc[i][j][r] += sold[row*M_ + col];
      }
  #pragma unroll
  for (int i=0;i<4;i++)
    #pragma unroll
    for (int r=0;r<4;r++){
      float ps = 0.f, qs = 0.f;
      #pragma unroll
      for (int j=0;j<4;j++){ float t = acc[i][j][r]; ps += t; qs += t*t; }
      ps += __shfl_xor(ps,1); qs += __shfl_xor(qs,1);
      ps += __shfl_xor(ps,2); qs += __shfl_xor(qs,2);
      ps += __shfl_xor(ps,4); qs += __shfl_xor(qs,4);
      ps += __shfl_xor(ps,8); qs += __shfl_xor(qs,8);
      if (lr == 0){
        int rowl = wy*64 + i*16 + g*4 + r;
        zs[wx][rowl][0] = ps;
        zs[wx][rowl][1] = qs;
      }
    }
  __syncthreads();
  #pragma unroll
  for (int i=0;i<4;i++)
    #pragma unroll
    for (int r=0;r<4;r++){
      int rowl = wy*64 + i*16 + g*4 + r;
      float sum = zs[0][rowl][0]+zs[1][rowl][0]+zs[2][rowl][0]+zs[3][rowl][0];
      float sq  = zs[0][rowl][1]+zs[1][rowl][1]+zs[2][rowl][1]+zs[3][rowl][1];
      float mean = sum*(1.f/M_);
      float var  = sq*(1.f/M_) - mean*mean;
      float rstd = rsqrtf(var + 1e-5f);
      int row = rowbase + rowl;
      #pragma unroll
      for (int j=0;j<4;j++){
        int col = wx*64 + j*16 + lr;
        float zv = acc[i][j][r];
        P1[row*M_ + col] = f2h((zv-mean)*rstd*lg[col] + lb[col] + zv);
      }
    }
}

// ---------------- fused MLP + LN: z = gelu(smid@fc1^T+b1)@fc2^T + b2; out=z, P1=f16(LN(z)) ----------------
// 128 rows/block, 8 c-chunks of 128 fcols. Double-buffered staging: ONE barrier per K-tile.
// Sbuf[2][16K u16]: FC1 tile = A(128x64)@0 + B1(128x64)@8192; FC2 tile = B2(256x64)@0.
__global__ __launch_bounds__(512) void k_fc(u16* __restrict__ P1,
    const u16* __restrict__ W1, const float* __restrict__ b1,
    const u16* __restrict__ W2, const float* __restrict__ b2,
    const float* __restrict__ lg, const float* __restrict__ lb,
    float* __restrict__ out){
  __shared__ __align__(16) u16 Sbuf[2][16384];  // 64KB
  __shared__ __align__(16) u16 Hbuf[128*128];   // 32KB
  __shared__ float zs[4][128][2];               // 4KB
  int tid = threadIdx.x;
  int wid = tid>>6, lane = tid&63;
  int wy = wid>>2, wx = wid&3;
  int g = lane>>4, lr = lane&15;
  int rowbase = blockIdx.x*128;

  auto stage_fc1 = [&](int c, int k0, int b){
    u16* S = Sbuf[b];
    #pragma unroll
    for (int it=0; it<2; it++){
      int idx = tid + it*512; int row = idx>>3, s = idx&7;
      *(uint4*)(S + row*64 + ((s^row)&7)*8) = *(const uint4*)(P1 + (rowbase+row)*M_ + k0 + s*8);
    }
    #pragma unroll
    for (int it=0; it<2; it++){
      int idx = tid + it*512; int row = idx>>3, s = idx&7;
      *(uint4*)(S + 8192 + row*64 + ((s^row)&7)*8) = *(const uint4*)(W1 + (c*128+row)*M_ + k0 + s*8);
    }
  };
  auto stage_fc2 = [&](int c, int kcl, int b){
    u16* S = Sbuf[b];
    #pragma unroll
    for (int it=0; it<4; it++){
      int idx = tid + it*512; int row = idx>>3, s = idx&7;
      *(uint4*)(S + row*64 + ((s^row)&7)*8) = *(const uint4*)(W2 + row*FF_ + c*128 + kcl*64 + s*8);
    }
  };

  f32x4 acc2[4][4];
  #pragma unroll
  for (int i=0;i<4;i++)
    #pragma unroll
    for (int j=0;j<4;j++) acc2[i][j] = 0.f;

  int cur = 0;
  stage_fc1(0, 0, 0);
  __syncthreads();
  for (int c=0;c<8;c++){
    f32x4 acc1[2][4];   // [fcol frag][smidrow frag] (transposed C)
    #pragma unroll
    for (int i=0;i<2;i++)
      #pragma unroll
      for (int j=0;j<4;j++) acc1[i][j] = 0.f;
    // ---- FC1 (transposed): fcols [c*128,+128), K=256 ----
    for (int k0i=0;k0i<4;k0i++){
      if (k0i<3) stage_fc1(c, (k0i+1)*64, cur^1);
      else       stage_fc2(c, 0, cur^1);
      const u16* S = Sbuf[cur];
      #pragma unroll
      for (int st=0; st<2; st++){
        f16x8 aw[2], bs[4];
        #pragma unroll
        for (int i=0;i<2;i++) aw[i] = frag(S + 8192, wx*32 + i*16 + lr, st, g);
        #pragma unroll
        for (int j=0;j<4;j++) bs[j] = frag(S, wy*64 + j*16 + lr, st, g);
        #pragma unroll
        for (int i=0;i<2;i++)
          #pragma unroll
          for (int j=0;j<4;j++) acc1[i][j] = mfmah(aw[i], bs[j], acc1[i][j]);
      }
      if (k0i==3){
        // gelu -> Hbuf (A-frag format, XOR-swizzled); lane holds 4 consecutive fcols/row
        #pragma unroll
        for (int i=0;i<2;i++){
          int fl = wx*32 + i*16 + g*4;       // fcol local 0..127
          int kc = fl>>6, kloc = fl&63;
          #pragma unroll
          for (int j=0;j<4;j++){
            int smrow = wy*64 + j*16 + lr;
            u16x4 hv;
            #pragma unroll
            for (int r=0;r<4;r++){
              float xv = acc1[i][j][r] + b1[c*128 + fl + r];
              hv[r] = f2h(gelu_f(xv));
            }
            int phys = ((kloc>>3) ^ smrow) & 7;
            *(u16x4*)(Hbuf + smrow*128 + kc*64 + phys*8 + (kloc&7)) = hv;
          }
        }
      }
      __syncthreads();
      cur ^= 1;
    }
    // ---- FC2 partial: k in [c*128,+128), 256 out cols ----
    for (int kcl=0;kcl<2;kcl++){
      if (kcl==0)      stage_fc2(c, 1, cur^1);
      else if (c<7)    stage_fc1(c+1, 0, cur^1);
      const u16* S = Sbuf[cur];
      #pragma unroll
      for (int st=0; st<2; st++){
        f16x8 ah[4], b[4];
        #pragma unroll
        for (int i=0;i<4;i++){
          int hrow = wy*64 + i*16 + lr;
          int phys = (((st<<2)|g) ^ hrow) & 7;
          ah[i] = *(const f16x8*)(Hbuf + hrow*128 + kcl*64 + phys*8);
        }
        #pragma unroll
        for (int j=0;j<4;j++) b[j] = frag(S, wx*64 + j*16 + lr, st, g);
        #pragma unroll
        for (int i=0;i<4;i++)
          #pragma unroll
          for (int j=0;j<4;j++) acc2[i][j] = mfmah(ah[i], b[j], acc2[i][j]);
      }
      __syncthreads();
      cur ^= 1;
    }
  }
  // ---- epilogue: z = acc2 + b2 -> out; LN -> P1 ----
  #pragma unroll
  for (int i=0;i<4;i++)
    #pragma unroll
    for (int j=0;j<4;j++)
      #pragma unroll
      for (int r=0;r<4;r++){
        int row = rowbase + wy*64 + i*16 + g*4 + r;
        int col = wx*64 + j*16 + lr;
        acc2[i][j][r] += b2[col];
        out[row*M_ + col] = acc2[i][j][r];
      }
  #pragma unroll
  for (int i=0;i<4;i++)
    #pragma unroll
    for (int r=0;r<4;r++){
      float ps = 0.f, qs = 0.f;
      #pragma unroll
      for (int j=0;j<4;j++){ float t = acc2[i][j][r]; ps += t; qs += t*t; }
      ps += __shfl_xor(ps,1); qs += __shfl_xor(qs,1);
      ps += __shfl_xor(ps,2); qs += __shfl_xor(qs,2);
      ps += __shfl_xor(ps,4); qs += __shfl_xor(qs,4);
      ps += __shfl_xor(ps,8); qs += __shfl_xor(qs,8);
      if (lr == 0){
        int rowl = wy*64 + i*16 + g*4 + r;
        zs[wx][rowl][0] = ps;
        zs[wx][rowl][1] = qs;
      }
    }
  __syncthreads();
  #pragma unroll
  for (int i=0;i<4;i++)
    #pragma unroll
    for (int r=0;r<4;r++){
      int rowl = wy*64 + i*16 + g*4 + r;
      float sum = zs[0][rowl][0]+zs[1][rowl][0]+zs[2][rowl][0]+zs[3][rowl][0];
      float sq  = zs[0][rowl][1]+zs[1][rowl][1]+zs[2][rowl][1]+zs[3][rowl][1];
      float mean = sum*(1.f/M_);
      float var  = sq*(1.f/M_) - mean*mean;
      float rstd = rsqrtf(var + 1e-5f);
      int row = rowbase + rowl;
      #pragma unroll
      for (int j=0;j<4;j++){
        int col = wx*64 + j*16 + lr;
        P1[row*M_ + col] = f2h((acc2[i][j][r]-mean)*rstd*lg[col] + lb[col]);
      }
    }
}

extern "C" void kernel_launch(void* const* d_in, const int* in_sizes, int n_in,
                              void* d_out, int out_size, void* d_ws, size_t ws_size,
                              hipStream_t stream){
  const float* x      = (const float*)d_in[0];
  const float* weight = (const float*)d_in[1];
  const float* wqkv   = (const float*)d_in[2];
  const float* wo     = (const float*)d_in[3];
  const float* ln_g   = (const float*)d_in[4];
  const float* ln_b   = (const float*)d_in[5];
  const float* lnz_g  = (const float*)d_in[6];
  const float* lnz_b  = (const float*)d_in[7];
  const float* fc1_w  = (const float*)d_in[8];
  const float* fc1_b  = (const float*)d_in[9];
  const float* fc2_w  = (const float*)d_in[10];
  const float* fc2_b  = (const float*)d_in[11];
  float* out = (float*)d_out;
  char* ws = (char*)d_ws;
  size_t off = 0;
  u16* wqkv_h = (u16*)(ws + off); off += 1572864;   // 4*768*256*2
  u16* wo_h   = (u16*)(ws + off); off += 524288;
  u16* fc1_h  = (u16*)(ws + off); off += 524288;
  u16* fc2_h  = (u16*)(ws + off); off += 524288;
  u16* P1     = (u16*)(ws + off); off += 33554432;  // R*256 f16 (LN-out -> cumsum -> smid)
  u16* imv    = (u16*)(ws + off); off += 33554432;  // R*256 f16 pre-scan imv
  // bias(f32 512KB) + weight_h(128KB) alias imv head: dead before k_qkv writes imv
  float* bias     = (float*)imv;
  u16*   weight_h = (u16*)((char*)imv + 524288);

  k_bias<<<N_, M_, 0, stream>>>(bias);
  k_half<<<64, 256, 0, stream>>>(weight, weight_h, 65536/4);
  k_half_qkv<<<TK_*768, 256, 0, stream>>>(wqkv, wqkv_h);
  k_half<<<256, 256, 0, stream>>>(wo, wo_h, 262144/4);
  k_half<<<256, 256, 0, stream>>>(fc1_w, fc1_h, 262144/4);
  k_half<<<256, 256, 0, stream>>>(fc2_w, fc2_h, 262144/4);
  k_init<<<R_/128, 512, 0, stream>>>(x, weight_h, bias, ln_g, ln_b, out, P1);
  for (int a=0; a<TK_; a++){
    k_qkv<<<dim3(R_/128, 2), 512, 0, stream>>>(P1, wqkv_h + a*768*M_, imv);
    k_scan<<<L_, 256, 0, stream>>>(imv, P1);
    k_wo<<<R_/128, 512, 0, stream>>>(P1, wo_h + a*65536, out, lnz_g, lnz_b);
    k_fc<<<R_/128, 512, 0, stream>>>(P1, fc1_h, fc1_b, fc2_h, fc2_b, ln_g, ln_b, out);
  }
}

// Round 8
// 994.883 us; speedup vs baseline: 4.2540x; 1.0658x over previous
//
#include <hip/hip_runtime.h>

typedef unsigned int u32;
typedef unsigned short u16;
typedef _Float16 f16;
typedef __attribute__((ext_vector_type(8))) _Float16 f16x8;
typedef __attribute__((ext_vector_type(4))) float f32x4;
typedef __attribute__((ext_vector_type(4))) u16 u16x4;

#define L_ 128
#define N_ 512
#define M_ 256
#define TK_ 4
#define H_ 8
#define R_ (L_*N_)
#define FF_ 1024

__device__ __forceinline__ u16 f2h(float v){ f16 h=(f16)v; return __builtin_bit_cast(u16,h); }
__device__ __forceinline__ float h2f(u16 b){ return (float)__builtin_bit_cast(f16,b); }
__device__ __forceinline__ f32x4 mfmah(f16x8 a, f16x8 b, f32x4 c){
  return __builtin_amdgcn_mfma_f32_16x16x32_f16(a,b,c,0,0,0);
}
// LDS tile: [row][8 slots of 8 f16], row stride 64 u16 (128B), slot XOR-swizzled by row&7.
__device__ __forceinline__ f16x8 frag(const u16* buf, int row, int st, int g){
  int sl = (((st<<2)|g) ^ row) & 7;
  return *(const f16x8*)(buf + row*64 + sl*8);
}
// tanh-form gelu: x*(1 - 1/(exp(2u)+1)), u = x*(c1 + c2*x^2). max err vs erf-gelu ~3e-4
__device__ __forceinline__ float gelu_f(float x){
  float u = x*(0.7978845608f + 0.0356774081f*x*x);
  float e = __expf(u + u);
  float r = __builtin_amdgcn_rcpf(e + 1.f);
  return x - x*r;
}

struct St4 { uint4 r[4]; };

// ---------------- prep ----------------
__global__ void k_bias(float* __restrict__ bias){
  int j = blockIdx.x, l = threadIdx.x;
  int t = l>>1;
  float base = expf(-0.14391156831212757f * (float)t); // ln(10000)/64
  float ang = (float)j * base;
  bias[j*M_ + l] = (l&1) ? cosf(ang) : sinf(ang);
}

__global__ void k_half(const float* __restrict__ src, u16* __restrict__ dst, int n4){
  int i = blockIdx.x*256 + threadIdx.x;
  if (i < n4){
    float4 v = ((const float4*)src)[i];
    u16x4 o;
    o[0]=f2h(v.x); o[1]=f2h(v.y); o[2]=f2h(v.z); o[3]=f2h(v.w);
    *(u16x4*)(dst + i*4) = o;
  }
}

// Wqkv[a,x,hd,d,m] -> f16 [a][hd*96 + x*32 + d][m]
__global__ void k_half_qkv(const float* __restrict__ w, u16* __restrict__ dst){
  int b = blockIdx.x, m = threadIdx.x;
  int a = b/768, colp = b%768;
  int hd = colp/96, rem = colp%96, x = rem/32, d = rem&31;
  dst[b*M_ + m] = f2h(w[(((a*3 + x)*H_ + hd)*32 + d)*M_ + m]);
}

// ---------------- k_init: z = x @ weight^T + bias; out=z, P1=f16(LN(z)) ----------------
__global__ __launch_bounds__(512) void k_init(const float* __restrict__ X, const u16* __restrict__ Wh,
    const float* __restrict__ bias, const float* __restrict__ lg, const float* __restrict__ lb,
    float* __restrict__ out, u16* __restrict__ P1){
  __shared__ __align__(16) u16 Abuf[128*64];
  __shared__ __align__(16) u16 Bbuf[256*64];
  __shared__ float zs[4][128][2];
  int tid = threadIdx.x;
  int wid = tid>>6, lane = tid&63;
  int wy = wid>>2, wx = wid&3;
  int g = lane>>4, lr = lane&15;
  int rowbase = blockIdx.x*128;
  f32x4 acc[4][4];
  #pragma unroll
  for (int i=0;i<4;i++)
    #pragma unroll
    for (int j=0;j<4;j++) acc[i][j] = 0.f;
  for (int k0=0;k0<M_;k0+=64){
    #pragma unroll
    for (int it=0; it<2; it++){ // A: 128 rows x 8 slots, f32->f16
      int idx = tid + it*512; int row = idx>>3, s = idx&7;
      const float* sp = X + (rowbase+row)*M_ + k0 + s*8;
      float4 v0 = *(const float4*)sp, v1 = *(const float4*)(sp+4);
      float vv[8] = {v0.x,v0.y,v0.z,v0.w,v1.x,v1.y,v1.z,v1.w};
      f16x8 hv;
      #pragma unroll
      for (int e=0;e<8;e++) hv[e] = (f16)vv[e];
      *(f16x8*)(Abuf + row*64 + ((s^row)&7)*8) = hv;
    }
    #pragma unroll
    for (int it=0; it<4; it++){ // B: 256 rows x 8 slots
      int idx = tid + it*512; int row = idx>>3, s = idx&7;
      *(uint4*)(Bbuf + row*64 + ((s^row)&7)*8) = *(const uint4*)(Wh + row*M_ + k0 + s*8);
    }
    __syncthreads();
    #pragma unroll
    for (int st=0; st<2; st++){
      f16x8 a[4], b[4];
      #pragma unroll
      for (int i=0;i<4;i++) a[i] = frag(Abuf, wy*64 + i*16 + lr, st, g);
      #pragma unroll
      for (int j=0;j<4;j++) b[j] = frag(Bbuf, wx*64 + j*16 + lr, st, g);
      #pragma unroll
      for (int i=0;i<4;i++)
        #pragma unroll
        for (int j=0;j<4;j++) acc[i][j] = mfmah(a[i], b[j], acc[i][j]);
    }
    __syncthreads();
  }
  // z = acc + bias -> out; LN epilogue -> P1
  #pragma unroll
  for (int i=0;i<4;i++)
    #pragma unroll
    for (int j=0;j<4;j++)
      #pragma unroll
      for (int r=0;r<4;r++){
        int row = rowbase + wy*64 + i*16 + g*4 + r;
        int col = wx*64 + j*16 + lr;
        acc[i][j][r] += bias[(row & (N_-1))*M_ + col];
        out[row*M_ + col] = acc[i][j][r];
      }
  #pragma unroll
  for (int i=0;i<4;i++)
    #pragma unroll
    for (int r=0;r<4;r++){
      float ps = 0.f, qs = 0.f;
      #pragma unroll
      for (int j=0;j<4;j++){ float t = acc[i][j][r]; ps += t; qs += t*t; }
      ps += __shfl_xor(ps,1); qs += __shfl_xor(qs,1);
      ps += __shfl_xor(ps,2); qs += __shfl_xor(qs,2);
      ps += __shfl_xor(ps,4); qs += __shfl_xor(qs,4);
      ps += __shfl_xor(ps,8); qs += __shfl_xor(qs,8);
      if (lr == 0){
        int rowl = wy*64 + i*16 + g*4 + r;
        zs[wx][rowl][0] = ps;
        zs[wx][rowl][1] = qs;
      }
    }
  __syncthreads();
  #pragma unroll
  for (int i=0;i<4;i++)
    #pragma unroll
    for (int r=0;r<4;r++){
      int rowl = wy*64 + i*16 + g*4 + r;
      float sum = zs[0][rowl][0]+zs[1][rowl][0]+zs[2][rowl][0]+zs[3][rowl][0];
      float sq  = zs[0][rowl][1]+zs[1][rowl][1]+zs[2][rowl][1]+zs[3][rowl][1];
      float mean = sum*(1.f/M_);
      float var  = sq*(1.f/M_) - mean*mean;
      float rstd = rsqrtf(var + 1e-5f);
      int row = rowbase + rowl;
      #pragma unroll
      for (int j=0;j<4;j++){
        int col = wx*64 + j*16 + lr;
        P1[row*M_ + col] = f2h((acc[i][j][r]-mean)*rstd*lg[col] + lb[col]);
      }
    }
}

// ---------------- QKV GEMM + fused rsa -> imv(f16) ----------------
__global__ __launch_bounds__(512) void k_qkv(const u16* __restrict__ P1, const u16* __restrict__ Wq,
    u16* __restrict__ imv){
  __shared__ __align__(16) u16 Abuf[128*64];
  __shared__ __align__(16) u16 Bbuf[384*64];
  int tid = threadIdx.x;
  int wid = tid>>6, lane = tid&63;
  int hd = wid>>1, sub = wid&1;
  int g = lane>>4, lr = lane&15;
  int rowbase = blockIdx.x*128;
  int hbase = blockIdx.y*384;
  f32x4 acc[4][6];
  #pragma unroll
  for (int i=0;i<4;i++)
    #pragma unroll
    for (int c=0;c<6;c++) acc[i][c] = 0.f;
  for (int k0=0;k0<M_;k0+=64){
    #pragma unroll
    for (int it=0; it<2; it++){ // A: 128 rows
      int idx = tid + it*512; int row = idx>>3, s = idx&7;
      *(uint4*)(Abuf + row*64 + ((s^row)&7)*8) = *(const uint4*)(P1 + (rowbase+row)*M_ + k0 + s*8);
    }
    #pragma unroll
    for (int it=0; it<6; it++){ // B: 384 rows
      int idx = tid + it*512; int row = idx>>3, s = idx&7;
      *(uint4*)(Bbuf + row*64 + ((s^row)&7)*8) = *(const uint4*)(Wq + (hbase+row)*M_ + k0 + s*8);
    }
    __syncthreads();
    #pragma unroll
    for (int st=0; st<2; st++){
      f16x8 a[4];
      #pragma unroll
      for (int i=0;i<4;i++) a[i] = frag(Abuf, sub*64 + i*16 + lr, st, g);
      #pragma unroll
      for (int c=0;c<6;c++){
        f16x8 b = frag(Bbuf, hd*96 + c*16 + lr, st, g);
        #pragma unroll
        for (int i=0;i<4;i++) acc[i][c] = mfmah(a[i], b, acc[i][c]);
      }
    }
    __syncthreads();
  }
  const float isd = 0.17677669529663687f; // 1/sqrt(32)
  int head = blockIdx.y*4 + hd;
  #pragma unroll
  for (int i=0;i<4;i++){
    f32x4 p = acc[i][0]*acc[i][2] + acc[i][1]*acc[i][3];
    #pragma unroll
    for (int r=0;r<4;r++){
      float v = p[r];
      v += __shfl_xor(v,1); v += __shfl_xor(v,2);
      v += __shfl_xor(v,4); v += __shfl_xor(v,8);
      float rsa = v * isd;
      int row = rowbase + sub*64 + i*16 + g*4 + r;
      imv[row*M_ + head*32 + lr]      = f2h(rsa*acc[i][4][r]);
      imv[row*M_ + head*32 + 16 + lr] = f2h(rsa*acc[i][5][r]);
    }
  }
}

// ---------------- cumsum over j: hierarchical, grid (L_*4), block (64m x 4jc) ----------------
__global__ __launch_bounds__(256) void k_scan(const u16* __restrict__ imv, u16* __restrict__ P1){
  __shared__ float tot[4][64];
  int bi = blockIdx.x;
  int i = bi>>2, mc = bi&3;
  int tid = threadIdx.x;
  int ml = tid&63, jc = tid>>6;
  int m = mc*64 + ml;
  int base = i*N_*M_ + jc*128*M_ + m;
  float acc = 0.f;
  for (int jb=0;jb<128;jb+=8){
    float t[8];
    #pragma unroll
    for (int u=0;u<8;u++) t[u] = h2f(imv[base + (jb+u)*M_]);
    #pragma unroll
    for (int u=0;u<8;u++) acc += t[u];
  }
  tot[jc][ml] = acc;
  __syncthreads();
  float pre = 0.f;
  #pragma unroll
  for (int q=0;q<3;q++) if (q<jc) pre += tot[q][ml];
  acc = pre;
  for (int jb=0;jb<128;jb+=8){
    float t[8];
    #pragma unroll
    for (int u=0;u<8;u++) t[u] = h2f(imv[base + (jb+u)*M_]);
    #pragma unroll
    for (int u=0;u<8;u++){ acc += t[u]; P1[base + (jb+u)*M_] = f2h(acc); }
  }
}

// ---------------- Wo GEMM + s_old + LN + residual -> P1(f16, in-place) ----------------
__global__ __launch_bounds__(512) void k_wo(u16* __restrict__ P1, const u16* __restrict__ Wh,
    const float* __restrict__ sold, const float* __restrict__ lg, const float* __restrict__ lb){
  __shared__ __align__(16) u16 Abuf[128*64];
  __shared__ __align__(16) u16 Bbuf[256*64];
  __shared__ float zs[4][128][2];
  int tid = threadIdx.x;
  int wid = tid>>6, lane = tid&63;
  int wy = wid>>2, wx = wid&3;
  int g = lane>>4, lr = lane&15;
  int rowbase = blockIdx.x*128;
  f32x4 acc[4][4];
  #pragma unroll
  for (int i=0;i<4;i++)
    #pragma unroll
    for (int j=0;j<4;j++) acc[i][j] = 0.f;
  for (int k0=0;k0<M_;k0+=64){
    #pragma unroll
    for (int it=0; it<2; it++){
      int idx = tid + it*512; int row = idx>>3, s = idx&7;
      *(uint4*)(Abuf + row*64 + ((s^row)&7)*8) = *(const uint4*)(P1 + (rowbase+row)*M_ + k0 + s*8);
    }
    #pragma unroll
    for (int it=0; it<4; it++){
      int idx = tid + it*512; int row = idx>>3, s = idx&7;
      *(uint4*)(Bbuf + row*64 + ((s^row)&7)*8) = *(const uint4*)(Wh + row*M_ + k0 + s*8);
    }
    __syncthreads();
    #pragma unroll
    for (int st=0; st<2; st++){
      f16x8 a[4], b[4];
      #pragma unroll
      for (int i=0;i<4;i++) a[i] = frag(Abuf, wy*64 + i*16 + lr, st, g);
      #pragma unroll
      for (int j=0;j<4;j++) b[j] = frag(Bbuf, wx*64 + j*16 + lr, st, g);
      #pragma unroll
      for (int i=0;i<4;i++)
        #pragma unroll
        for (int j=0;j<4;j++) acc[i][j] = mfmah(a[i], b[j], acc[i][j]);
    }
    __syncthreads();
  }
  #pragma unroll
  for (int i=0;i<4;i++)
    #pragma unroll
    for (int j=0;j<4;j++)
      #pragma unroll
      for (int r=0;r<4;r++){
        int row = rowbase + wy*64 + i*16 + g*4 + r;
        int col = wx*64 + j*16 + lr;
        acc[i][j][r] += sold[row*M_ + col];
      }
  #pragma unroll
  for (int i=0;i<4;i++)
    #pragma unroll
    for (int r=0;r<4;r++){
      float ps = 0.f, qs = 0.f;
      #pragma unroll
      for (int j=0;j<4;j++){ float t = acc[i][j][r]; ps += t; qs += t*t; }
      ps += __shfl_xor(ps,1); qs += __shfl_xor(qs,1);
      ps += __shfl_xor(ps,2); qs += __shfl_xor(qs,2);
      ps += __shfl_xor(ps,4); qs += __shfl_xor(qs,4);
      ps += __shfl_xor(ps,8); qs += __shfl_xor(qs,8);
      if (lr == 0){
        int rowl = wy*64 + i*16 + g*4 + r;
        zs[wx][rowl][0] = ps;
        zs[wx][rowl][1] = qs;
      }
    }
  __syncthreads();
  #pragma unroll
  for (int i=0;i<4;i++)
    #pragma unroll
    for (int r=0;r<4;r++){
      int rowl = wy*64 + i*16 + g*4 + r;
      float sum = zs[0][rowl][0]+zs[1][rowl][0]+zs[2][rowl][0]+zs[3][rowl][0];
      float sq  = zs[0][rowl][1]+zs[1][rowl][1]+zs[2][rowl][1]+zs[3][rowl][1];
      float mean = sum*(1.f/M_);
      float var  = sq*(1.f/M_) - mean*mean;
      float rstd = rsqrtf(var + 1e-5f);
      int row = rowbase + rowl;
      #pragma unroll
      for (int j=0;j<4;j++){
        int col = wx*64 + j*16 + lr;
        float zv = acc[i][j][r];
        P1[row*M_ + col] = f2h((zv-mean)*rstd*lg[col] + lb[col] + zv);
      }
    }
}

// ---------------- fused MLP + LN: z = gelu(smid@fc1^T+b1)@fc2^T + b2; out=z, P1=f16(LN(z)) ----------------
// T14 async-stage: global loads (regs) issued BEFORE compute, ds_write AFTER, one barrier/tile.
__global__ __launch_bounds__(512) void k_fc(u16* __restrict__ P1,
    const u16* __restrict__ W1, const float* __restrict__ b1,
    const u16* __restrict__ W2, const float* __restrict__ b2,
    const float* __restrict__ lg, const float* __restrict__ lb,
    float* __restrict__ out){
  __shared__ __align__(16) u16 Sbuf[2][16384];  // 64KB
  __shared__ __align__(16) u16 Hbuf[128*128];   // 32KB
  __shared__ float zs[4][128][2];               // 4KB
  int tid = threadIdx.x;
  int wid = tid>>6, lane = tid&63;
  int wy = wid>>2, wx = wid&3;
  int g = lane>>4, lr = lane&15;
  int rowbase = blockIdx.x*128;

  auto load_fc1 = [&](int c, int k0){
    St4 o;
    #pragma unroll
    for (int it=0; it<2; it++){
      int idx = tid + it*512; int row = idx>>3, s = idx&7;
      o.r[it] = *(const uint4*)(P1 + (rowbase+row)*M_ + k0 + s*8);
    }
    #pragma unroll
    for (int it=0; it<2; it++){
      int idx = tid + it*512; int row = idx>>3, s = idx&7;
      o.r[2+it] = *(const uint4*)(W1 + (c*128+row)*M_ + k0 + s*8);
    }
    return o;
  };
  auto write_fc1 = [&](const St4& v, int b){
    u16* S = Sbuf[b];
    #pragma unroll
    for (int it=0; it<2; it++){
      int idx = tid + it*512; int row = idx>>3, s = idx&7;
      *(uint4*)(S + row*64 + ((s^row)&7)*8) = v.r[it];
    }
    #pragma unroll
    for (int it=0; it<2; it++){
      int idx = tid + it*512; int row = idx>>3, s = idx&7;
      *(uint4*)(S + 8192 + row*64 + ((s^row)&7)*8) = v.r[2+it];
    }
  };
  auto load_fc2 = [&](int c, int kcl){
    St4 o;
    #pragma unroll
    for (int it=0; it<4; it++){
      int idx = tid + it*512; int row = idx>>3, s = idx&7;
      o.r[it] = *(const uint4*)(W2 + row*FF_ + c*128 + kcl*64 + s*8);
    }
    return o;
  };
  auto write_fc2 = [&](const St4& v, int b){
    u16* S = Sbuf[b];
    #pragma unroll
    for (int it=0; it<4; it++){
      int idx = tid + it*512; int row = idx>>3, s = idx&7;
      *(uint4*)(S + row*64 + ((s^row)&7)*8) = v.r[it];
    }
  };

  f32x4 acc2[4][4];
  #pragma unroll
  for (int i=0;i<4;i++)
    #pragma unroll
    for (int j=0;j<4;j++) acc2[i][j] = 0.f;

  int cur = 0;
  { St4 p0 = load_fc1(0, 0); write_fc1(p0, 0); }
  __syncthreads();
  for (int c=0;c<8;c++){
    f32x4 acc1[2][4];   // [fcol frag][smidrow frag] (transposed C)
    #pragma unroll
    for (int i=0;i<2;i++)
      #pragma unroll
      for (int j=0;j<4;j++) acc1[i][j] = 0.f;
    // ---- FC1 (transposed): fcols [c*128,+128), K=256 ----
    for (int k0i=0;k0i<4;k0i++){
      St4 nxt;
      if (k0i<3) nxt = load_fc1(c, (k0i+1)*64);
      else       nxt = load_fc2(c, 0);
      const u16* S = Sbuf[cur];
      #pragma unroll
      for (int st=0; st<2; st++){
        f16x8 aw[2], bs[4];
        #pragma unroll
        for (int i=0;i<2;i++) aw[i] = frag(S + 8192, wx*32 + i*16 + lr, st, g);
        #pragma unroll
        for (int j=0;j<4;j++) bs[j] = frag(S, wy*64 + j*16 + lr, st, g);
        #pragma unroll
        for (int i=0;i<2;i++)
          #pragma unroll
          for (int j=0;j<4;j++) acc1[i][j] = mfmah(aw[i], bs[j], acc1[i][j]);
      }
      if (k0i==3){
        // gelu -> Hbuf (A-frag format, XOR-swizzled); lane holds 4 consecutive fcols/row
        #pragma unroll
        for (int i=0;i<2;i++){
          int fl = wx*32 + i*16 + g*4;       // fcol local 0..127
          int kc = fl>>6, kloc = fl&63;
          #pragma unroll
          for (int j=0;j<4;j++){
            int smrow = wy*64 + j*16 + lr;
            u16x4 hv;
            #pragma unroll
            for (int r=0;r<4;r++){
              float xv = acc1[i][j][r] + b1[c*128 + fl + r];
              hv[r] = f2h(gelu_f(xv));
            }
            int phys = ((kloc>>3) ^ smrow) & 7;
            *(u16x4*)(Hbuf + smrow*128 + kc*64 + phys*8 + (kloc&7)) = hv;
          }
        }
      }
      if (k0i<3) write_fc1(nxt, cur^1);
      else       write_fc2(nxt, cur^1);
      __syncthreads();
      cur ^= 1;
    }
    // ---- FC2 partial: k in [c*128,+128), 256 out cols ----
    for (int kcl=0;kcl<2;kcl++){
      St4 nxt;
      bool havext = (kcl==0) || (c<7);
      if (kcl==0)   nxt = load_fc2(c, 1);
      else if (c<7) nxt = load_fc1(c+1, 0);
      const u16* S = Sbuf[cur];
      #pragma unroll
      for (int st=0; st<2; st++){
        f16x8 ah[4], b[4];
        #pragma unroll
        for (int i=0;i<4;i++){
          int hrow = wy*64 + i*16 + lr;
          int phys = (((st<<2)|g) ^ hrow) & 7;
          ah[i] = *(const f16x8*)(Hbuf + hrow*128 + kcl*64 + phys*8);
        }
        #pragma unroll
        for (int j=0;j<4;j++) b[j] = frag(S, wx*64 + j*16 + lr, st, g);
        #pragma unroll
        for (int i=0;i<4;i++)
          #pragma unroll
          for (int j=0;j<4;j++) acc2[i][j] = mfmah(ah[i], b[j], acc2[i][j]);
      }
      if (havext){
        if (kcl==0) write_fc2(nxt, cur^1);
        else        write_fc1(nxt, cur^1);
      }
      __syncthreads();
      cur ^= 1;
    }
  }
  // ---- epilogue: z = acc2 + b2 -> out; LN -> P1 ----
  #pragma unroll
  for (int i=0;i<4;i++)
    #pragma unroll
    for (int j=0;j<4;j++)
      #pragma unroll
      for (int r=0;r<4;r++){
        int row = rowbase + wy*64 + i*16 + g*4 + r;
        int col = wx*64 + j*16 + lr;
        acc2[i][j][r] += b2[col];
        out[row*M_ + col] = acc2[i][j][r];
      }
  #pragma unroll
  for (int i=0;i<4;i++)
    #pragma unroll
    for (int r=0;r<4;r++){
      float ps = 0.f, qs = 0.f;
      #pragma unroll
      for (int j=0;j<4;j++){ float t = acc2[i][j][r]; ps += t; qs += t*t; }
      ps += __shfl_xor(ps,1); qs += __shfl_xor(qs,1);
      ps += __shfl_xor(ps,2); qs += __shfl_xor(qs,2);
      ps += __shfl_xor(ps,4); qs += __shfl_xor(qs,4);
      ps += __shfl_xor(ps,8); qs += __shfl_xor(qs,8);
      if (lr == 0){
        int rowl = wy*64 + i*16 + g*4 + r;
        zs[wx][rowl][0] = ps;
        zs[wx][rowl][1] = qs;
      }
    }
  __syncthreads();
  #pragma unroll
  for (int i=0;i<4;i++)
    #pragma unroll
    for (int r=0;r<4;r++){
      int rowl = wy*64 + i*16 + g*4 + r;
      float sum = zs[0][rowl][0]+zs[1][rowl][0]+zs[2][rowl][0]+zs[3][rowl][0];
      float sq  = zs[0][rowl][1]+zs[1][rowl][1]+zs[2][rowl][1]+zs[3][rowl][1];
      float mean = sum*(1.f/M_);
      float var  = sq*(1.f/M_) - mean*mean;
      float rstd = rsqrtf(var + 1e-5f);
      int row = rowbase + rowl;
      #pragma unroll
      for (int j=0;j<4;j++){
        int col = wx*64 + j*16 + lr;
        P1[row*M_ + col] = f2h((acc2[i][j][r]-mean)*rstd*lg[col] + lb[col]);
      }
    }
}

extern "C" void kernel_launch(void* const* d_in, const int* in_sizes, int n_in,
                              void* d_out, int out_size, void* d_ws, size_t ws_size,
                              hipStream_t stream){
  const float* x      = (const float*)d_in[0];
  const float* weight = (const float*)d_in[1];
  const float* wqkv   = (const float*)d_in[2];
  const float* wo     = (const float*)d_in[3];
  const float* ln_g   = (const float*)d_in[4];
  const float* ln_b   = (const float*)d_in[5];
  const float* lnz_g  = (const float*)d_in[6];
  const float* lnz_b  = (const float*)d_in[7];
  const float* fc1_w  = (const float*)d_in[8];
  const float* fc1_b  = (const float*)d_in[9];
  const float* fc2_w  = (const float*)d_in[10];
  const float* fc2_b  = (const float*)d_in[11];
  float* out = (float*)d_out;
  char* ws = (char*)d_ws;
  size_t off = 0;
  u16* wqkv_h = (u16*)(ws + off); off += 1572864;   // 4*768*256*2
  u16* wo_h   = (u16*)(ws + off); off += 524288;
  u16* fc1_h  = (u16*)(ws + off); off += 524288;
  u16* fc2_h  = (u16*)(ws + off); off += 524288;
  u16* P1     = (u16*)(ws + off); off += 33554432;  // R*256 f16 (LN-out -> cumsum -> smid)
  u16* imv    = (u16*)(ws + off); off += 33554432;  // R*256 f16 pre-scan imv
  // bias(f32 512KB) + weight_h(128KB) alias imv head: dead before k_qkv writes imv
  float* bias     = (float*)imv;
  u16*   weight_h = (u16*)((char*)imv + 524288);

  k_bias<<<N_, M_, 0, stream>>>(bias);
  k_half<<<64, 256, 0, stream>>>(weight, weight_h, 65536/4);
  k_half_qkv<<<TK_*768, 256, 0, stream>>>(wqkv, wqkv_h);
  k_half<<<256, 256, 0, stream>>>(wo, wo_h, 262144/4);
  k_half<<<256, 256, 0, stream>>>(fc1_w, fc1_h, 262144/4);
  k_half<<<256, 256, 0, stream>>>(fc2_w, fc2_h, 262144/4);
  k_init<<<R_/128, 512, 0, stream>>>(x, weight_h, bias, ln_g, ln_b, out, P1);
  for (int a=0; a<TK_; a++){
    k_qkv<<<dim3(R_/128, 2), 512, 0, stream>>>(P1, wqkv_h + a*768*M_, imv);
    k_scan<<<L_*4, 256, 0, stream>>>(imv, P1);
    k_wo<<<R_/128, 512, 0, stream>>>(P1, wo_h + a*65536, out, lnz_g, lnz_b);
    k_fc<<<R_/128, 512, 0, stream>>>(P1, fc1_h, fc1_b, fc2_h, fc2_b, ln_g, ln_b, out);
  }
}

// Round 9
// 989.479 us; speedup vs baseline: 4.2772x; 1.0055x over previous
//
#include <hip/hip_runtime.h>

typedef unsigned int u32;
typedef unsigned short u16;
typedef _Float16 f16;
typedef __attribute__((ext_vector_type(8))) _Float16 f16x8;
typedef __attribute__((ext_vector_type(4))) float f32x4;
typedef __attribute__((ext_vector_type(4))) u16 u16x4;

#define L_ 128
#define N_ 512
#define M_ 256
#define TK_ 4
#define H_ 8
#define R_ (L_*N_)
#define FF_ 1024

__device__ __forceinline__ u16 f2h(float v){ f16 h=(f16)v; return __builtin_bit_cast(u16,h); }
__device__ __forceinline__ float h2f(u16 b){ return (float)__builtin_bit_cast(f16,b); }
__device__ __forceinline__ f32x4 mfmah(f16x8 a, f16x8 b, f32x4 c){
  return __builtin_amdgcn_mfma_f32_16x16x32_f16(a,b,c,0,0,0);
}
// tanh-form gelu
__device__ __forceinline__ float gelu_f(float x){
  float u = x*(0.7978845608f + 0.0356774081f*x*x);
  float e = __expf(u + u);
  float r = __builtin_amdgcn_rcpf(e + 1.f);
  return x - x*r;
}

// Frag-major packing: for weight W[C][K] (C out-cols, K reduction), tile (cg,k64):
//   dst[(cg*(K/64)+k64)*1024 + st*512 + g*128 + lr*8 + e] = W[cg*16+lr][k64*64+st*32+g*8+e]
// A wave reads one frag as 1KB contiguous: ptr + st*512 + (lane>>4)*128 + (lane&15)*8.

// ---------------- prep ----------------
__global__ void k_bias(float* __restrict__ bias){
  int j = blockIdx.x, l = threadIdx.x;
  int t = l>>1;
  float base = expf(-0.14391156831212757f * (float)t); // ln(10000)/64
  float ang = (float)j * base;
  bias[j*M_ + l] = (l&1) ? cosf(ang) : sinf(ang);
}

// generic f32 [C][K] -> frag-packed f16; grid = (C/16)*(K/64), block 128
__global__ void k_pack(const float* __restrict__ src, u16* __restrict__ dst, int K){
  int b = blockIdx.x; int nk = K>>6; int cg = b/nk, k64 = b%nk;
  int t = threadIdx.x;
  int st = t>>6, g = (t>>4)&3, lr = t&15;
  const float* sp = src + (cg*16+lr)*K + k64*64 + st*32 + g*8;
  f16x8 hv;
  #pragma unroll
  for (int e=0;e<8;e++) hv[e] = (f16)sp[e];
  *(f16x8*)(dst + b*1024 + t*8) = hv;
}

// Wqkv[a,x,hd,d,m] -> frag-packed per a: [grp=hd*6+cidx (48)][k64 (4)][1024]; grid 768, block 128
__global__ void k_pack_qkv(const float* __restrict__ w, u16* __restrict__ dst){
  int b = blockIdx.x;              // a*192 + grp*4 + k64
  int a = b/192; int rmn = b%192; int grp = rmn>>2, k64 = rmn&3;
  int hd = grp/6, cidx = grp%6;
  int t = threadIdx.x;
  int st = t>>6, g = (t>>4)&3, lr = t&15;
  int cl = cidx*16 + lr;           // 0..95
  int x = cl>>5, d = cl&31;
  const float* sp = w + (((a*3+x)*H_+hd)*32 + d)*M_ + k64*64 + st*32 + g*8;
  f16x8 hv;
  #pragma unroll
  for (int e=0;e<8;e++) hv[e] = (f16)sp[e];
  *(f16x8*)(dst + b*1024 + t*8) = hv;
}

// ---------------- k_init: z = x @ weight^T + bias; out=z, P1=f16(LN(z)) ----------------
// 128 rows/block, 8 waves (wy2 x wx4). A frag-packed in LDS once; B frag-direct from L2.
__global__ __launch_bounds__(512) void k_init(const float* __restrict__ X, const u16* __restrict__ Wf,
    const float* __restrict__ bias, const float* __restrict__ lg, const float* __restrict__ lb,
    float* __restrict__ out, u16* __restrict__ P1){
  __shared__ __align__(16) u16 Abuf[32*1024];   // [k64 4][rowgrp 8][1024] = 64KB
  __shared__ float zs[4][128][2];
  int tid = threadIdx.x;
  int wid = tid>>6, lane = tid&63;
  int wy = wid>>2, wx = wid&3;
  int g = lane>>4, lr = lane&15;
  int lo = g*128 + lr*8;
  int rowbase = blockIdx.x*128;
  { // stage A (f32 -> f16 frag-pack)
    int slr = tid&15, srg = (tid>>4)&7, sk = tid>>7;
    const float* sp = X + (rowbase + srg*16 + slr)*M_ + sk*64;
    u16* dp = Abuf + (sk*8 + srg)*1024 + slr*8;
    #pragma unroll
    for (int st=0;st<2;st++)
      #pragma unroll
      for (int gg=0;gg<4;gg++){
        const float* s2 = sp + st*32 + gg*8;
        f16x8 hv;
        #pragma unroll
        for (int e=0;e<8;e++) hv[e] = (f16)s2[e];
        *(f16x8*)(dp + st*512 + gg*128) = hv;
      }
  }
  __syncthreads();
  f32x4 acc[4][4];
  #pragma unroll
  for (int i=0;i<4;i++)
    #pragma unroll
    for (int j=0;j<4;j++) acc[i][j] = 0.f;
  #pragma unroll
  for (int k64=0;k64<4;k64++)
    #pragma unroll
    for (int st=0;st<2;st++){
      f16x8 a[4], b[4];
      #pragma unroll
      for (int i=0;i<4;i++) a[i] = *(const f16x8*)(Abuf + (k64*8 + wy*4 + i)*1024 + st*512 + lo);
      #pragma unroll
      for (int j=0;j<4;j++) b[j] = *(const f16x8*)(Wf + ((wx*4+j)*4 + k64)*1024 + st*512 + lo);
      #pragma unroll
      for (int i=0;i<4;i++)
        #pragma unroll
        for (int j=0;j<4;j++) acc[i][j] = mfmah(a[i], b[j], acc[i][j]);
    }
  // epilogue: +bias -> out; LN -> P1
  #pragma unroll
  for (int i=0;i<4;i++)
    #pragma unroll
    for (int j=0;j<4;j++)
      #pragma unroll
      for (int r=0;r<4;r++){
        int row = rowbase + wy*64 + i*16 + g*4 + r;
        int col = wx*64 + j*16 + lr;
        acc[i][j][r] += bias[(row & (N_-1))*M_ + col];
        out[row*M_ + col] = acc[i][j][r];
      }
  #pragma unroll
  for (int i=0;i<4;i++)
    #pragma unroll
    for (int r=0;r<4;r++){
      float ps = 0.f, qs = 0.f;
      #pragma unroll
      for (int j=0;j<4;j++){ float t = acc[i][j][r]; ps += t; qs += t*t; }
      ps += __shfl_xor(ps,1); qs += __shfl_xor(qs,1);
      ps += __shfl_xor(ps,2); qs += __shfl_xor(qs,2);
      ps += __shfl_xor(ps,4); qs += __shfl_xor(qs,4);
      ps += __shfl_xor(ps,8); qs += __shfl_xor(qs,8);
      if (lr == 0){
        int rowl = wy*64 + i*16 + g*4 + r;
        zs[wx][rowl][0] = ps;
        zs[wx][rowl][1] = qs;
      }
    }
  __syncthreads();
  #pragma unroll
  for (int i=0;i<4;i++)
    #pragma unroll
    for (int r=0;r<4;r++){
      int rowl = wy*64 + i*16 + g*4 + r;
      float sum = zs[0][rowl][0]+zs[1][rowl][0]+zs[2][rowl][0]+zs[3][rowl][0];
      float sq  = zs[0][rowl][1]+zs[1][rowl][1]+zs[2][rowl][1]+zs[3][rowl][1];
      float mean = sum*(1.f/M_);
      float var  = sq*(1.f/M_) - mean*mean;
      float rstd = rsqrtf(var + 1e-5f);
      int row = rowbase + rowl;
      #pragma unroll
      for (int j=0;j<4;j++){
        int col = wx*64 + j*16 + lr;
        P1[row*M_ + col] = f2h((acc[i][j][r]-mean)*rstd*lg[col] + lb[col]);
      }
    }
}

// ---------------- QKV GEMM + fused rsa -> imv(f16) ----------------
// grid (R/128, 2); 8 waves = (hd 0..3, sub 0..1). A in LDS once; Wqkv frag-direct.
__global__ __launch_bounds__(512) void k_qkv(const u16* __restrict__ P1, const u16* __restrict__ Wq,
    u16* __restrict__ imv){
  __shared__ __align__(16) u16 Abuf[32*1024];   // 64KB
  int tid = threadIdx.x;
  int wid = tid>>6, lane = tid&63;
  int hd = wid>>1, sub = wid&1;
  int g = lane>>4, lr = lane&15;
  int lo = g*128 + lr*8;
  int rowbase = blockIdx.x*128;
  int y = blockIdx.y;
  { // stage A (f16 copy, frag-pack)
    int slr = tid&15, srg = (tid>>4)&7, sk = tid>>7;
    const u16* sp = P1 + (rowbase + srg*16 + slr)*M_ + sk*64;
    u16* dp = Abuf + (sk*8 + srg)*1024 + slr*8;
    #pragma unroll
    for (int st=0;st<2;st++)
      #pragma unroll
      for (int gg=0;gg<4;gg++)
        *(uint4*)(dp + st*512 + gg*128) = *(const uint4*)(sp + st*32 + gg*8);
  }
  __syncthreads();
  f32x4 acc[4][6];
  #pragma unroll
  for (int i=0;i<4;i++)
    #pragma unroll
    for (int c=0;c<6;c++) acc[i][c] = 0.f;
  const u16* Wb = Wq + (y*24 + hd*6)*4096;   // grp*4*1024
  #pragma unroll
  for (int k64=0;k64<4;k64++)
    #pragma unroll
    for (int st=0;st<2;st++){
      f16x8 a[4];
      #pragma unroll
      for (int i=0;i<4;i++) a[i] = *(const f16x8*)(Abuf + (k64*8 + sub*4 + i)*1024 + st*512 + lo);
      #pragma unroll
      for (int c=0;c<6;c++){
        f16x8 b = *(const f16x8*)(Wb + (c*4 + k64)*1024 + st*512 + lo);
        #pragma unroll
        for (int i=0;i<4;i++) acc[i][c] = mfmah(a[i], b, acc[i][c]);
      }
    }
  const float isd = 0.17677669529663687f; // 1/sqrt(32)
  int head = y*4 + hd;
  #pragma unroll
  for (int i=0;i<4;i++){
    f32x4 p = acc[i][0]*acc[i][2] + acc[i][1]*acc[i][3];
    #pragma unroll
    for (int r=0;r<4;r++){
      float v = p[r];
      v += __shfl_xor(v,1); v += __shfl_xor(v,2);
      v += __shfl_xor(v,4); v += __shfl_xor(v,8);
      float rsa = v * isd;
      int row = rowbase + sub*64 + i*16 + g*4 + r;
      imv[row*M_ + head*32 + lr]      = f2h(rsa*acc[i][4][r]);
      imv[row*M_ + head*32 + 16 + lr] = f2h(rsa*acc[i][5][r]);
    }
  }
}

// ---------------- cumsum over j: hierarchical, grid (L_*4), block (64m x 4jc) ----------------
__global__ __launch_bounds__(256) void k_scan(const u16* __restrict__ imv, u16* __restrict__ P1){
  __shared__ float tot[4][64];
  int bi = blockIdx.x;
  int i = bi>>2, mc = bi&3;
  int tid = threadIdx.x;
  int ml = tid&63, jc = tid>>6;
  int m = mc*64 + ml;
  int base = i*N_*M_ + jc*128*M_ + m;
  float acc = 0.f;
  for (int jb=0;jb<128;jb+=8){
    float t[8];
    #pragma unroll
    for (int u=0;u<8;u++) t[u] = h2f(imv[base + (jb+u)*M_]);
    #pragma unroll
    for (int u=0;u<8;u++) acc += t[u];
  }
  tot[jc][ml] = acc;
  __syncthreads();
  float pre = 0.f;
  #pragma unroll
  for (int q=0;q<3;q++) if (q<jc) pre += tot[q][ml];
  acc = pre;
  for (int jb=0;jb<128;jb+=8){
    float t[8];
    #pragma unroll
    for (int u=0;u<8;u++) t[u] = h2f(imv[base + (jb+u)*M_]);
    #pragma unroll
    for (int u=0;u<8;u++){ acc += t[u]; P1[base + (jb+u)*M_] = f2h(acc); }
  }
}

// ---------------- Wo GEMM + s_old + LN + residual -> P1(f16, in-place) ----------------
__global__ __launch_bounds__(512) void k_wo(u16* __restrict__ P1, const u16* __restrict__ Wf,
    const float* __restrict__ sold, const float* __restrict__ lg, const float* __restrict__ lb){
  __shared__ __align__(16) u16 Abuf[32*1024];   // 64KB
  __shared__ float zs[4][128][2];
  int tid = threadIdx.x;
  int wid = tid>>6, lane = tid&63;
  int wy = wid>>2, wx = wid&3;
  int g = lane>>4, lr = lane&15;
  int lo = g*128 + lr*8;
  int rowbase = blockIdx.x*128;
  { // stage A
    int slr = tid&15, srg = (tid>>4)&7, sk = tid>>7;
    const u16* sp = P1 + (rowbase + srg*16 + slr)*M_ + sk*64;
    u16* dp = Abuf + (sk*8 + srg)*1024 + slr*8;
    #pragma unroll
    for (int st=0;st<2;st++)
      #pragma unroll
      for (int gg=0;gg<4;gg++)
        *(uint4*)(dp + st*512 + gg*128) = *(const uint4*)(sp + st*32 + gg*8);
  }
  __syncthreads();
  f32x4 acc[4][4];
  #pragma unroll
  for (int i=0;i<4;i++)
    #pragma unroll
    for (int j=0;j<4;j++) acc[i][j] = 0.f;
  #pragma unroll
  for (int k64=0;k64<4;k64++)
    #pragma unroll
    for (int st=0;st<2;st++){
      f16x8 a[4], b[4];
      #pragma unroll
      for (int i=0;i<4;i++) a[i] = *(const f16x8*)(Abuf + (k64*8 + wy*4 + i)*1024 + st*512 + lo);
      #pragma unroll
      for (int j=0;j<4;j++) b[j] = *(const f16x8*)(Wf + ((wx*4+j)*4 + k64)*1024 + st*512 + lo);
      #pragma unroll
      for (int i=0;i<4;i++)
        #pragma unroll
        for (int j=0;j<4;j++) acc[i][j] = mfmah(a[i], b[j], acc[i][j]);
    }
  #pragma unroll
  for (int i=0;i<4;i++)
    #pragma unroll
    for (int j=0;j<4;j++)
      #pragma unroll
      for (int r=0;r<4;r++){
        int row = rowbase + wy*64 + i*16 + g*4 + r;
        int col = wx*64 + j*16 + lr;
        acc[i][j][r] += sold[row*M_ + col];
      }
  #pragma unroll
  for (int i=0;i<4;i++)
    #pragma unroll
    for (int r=0;r<4;r++){
      float ps = 0.f, qs = 0.f;
      #pragma unroll
      for (int j=0;j<4;j++){ float t = acc[i][j][r]; ps += t; qs += t*t; }
      ps += __shfl_xor(ps,1); qs += __shfl_xor(qs,1);
      ps += __shfl_xor(ps,2); qs += __shfl_xor(qs,2);
      ps += __shfl_xor(ps,4); qs += __shfl_xor(qs,4);
      ps += __shfl_xor(ps,8); qs += __shfl_xor(qs,8);
      if (lr == 0){
        int rowl = wy*64 + i*16 + g*4 + r;
        zs[wx][rowl][0] = ps;
        zs[wx][rowl][1] = qs;
      }
    }
  __syncthreads();
  #pragma unroll
  for (int i=0;i<4;i++)
    #pragma unroll
    for (int r=0;r<4;r++){
      int rowl = wy*64 + i*16 + g*4 + r;
      float sum = zs[0][rowl][0]+zs[1][rowl][0]+zs[2][rowl][0]+zs[3][rowl][0];
      float sq  = zs[0][rowl][1]+zs[1][rowl][1]+zs[2][rowl][1]+zs[3][rowl][1];
      float mean = sum*(1.f/M_);
      float var  = sq*(1.f/M_) - mean*mean;
      float rstd = rsqrtf(var + 1e-5f);
      int row = rowbase + rowl;
      #pragma unroll
      for (int j=0;j<4;j++){
        int col = wx*64 + j*16 + lr;
        float zv = acc[i][j][r];
        P1[row*M_ + col] = f2h((zv-mean)*rstd*lg[col] + lb[col] + zv);
      }
    }
}

// ---------------- fused MLP + LN: z = gelu(smid@fc1^T+b1)@fc2^T + b2; out=z, P1=f16(LN(z)) ----------------
// 64 rows/block, 4 waves, 8 c-chunks of 128 fcols. A resident in LDS; W1/W2 frag-direct from L2.
__global__ __launch_bounds__(256) void k_fc(u16* __restrict__ P1,
    const u16* __restrict__ W1f, const float* __restrict__ b1,
    const u16* __restrict__ W2f, const float* __restrict__ b2,
    const float* __restrict__ lg, const float* __restrict__ lb,
    float* __restrict__ out){
  __shared__ __align__(16) u16 Abuf[16*1024];   // [k64 4][rowgrp 4][1024] = 32KB
  __shared__ __align__(16) u16 Hbuf[64*128];    // 16KB
  __shared__ float zs[4][64][2];                // 2KB
  int tid = threadIdx.x;
  int w = tid>>6, lane = tid&63;
  int g = lane>>4, lr = lane&15;
  int lo = g*128 + lr*8;
  int rowbase = blockIdx.x*64;
  { // stage A once
    int slr = tid&15, srg = (tid>>4)&3, sk = tid>>6;
    const u16* sp = P1 + (rowbase + srg*16 + slr)*M_ + sk*64;
    u16* dp = Abuf + (sk*4 + srg)*1024 + slr*8;
    #pragma unroll
    for (int st=0;st<2;st++)
      #pragma unroll
      for (int gg=0;gg<4;gg++)
        *(uint4*)(dp + st*512 + gg*128) = *(const uint4*)(sp + st*32 + gg*8);
  }
  __syncthreads();
  f32x4 acc2[4][4];
  #pragma unroll
  for (int i=0;i<4;i++)
    #pragma unroll
    for (int j=0;j<4;j++) acc2[i][j] = 0.f;
  for (int c=0;c<8;c++){
    f32x4 acc1[2][4];   // [fcol frag][smidrow frag] (C^T)
    #pragma unroll
    for (int i=0;i<2;i++)
      #pragma unroll
      for (int j=0;j<4;j++) acc1[i][j] = 0.f;
    // ---- FC1^T: fcols [c*128,+128); W1 frag-direct; A from LDS ----
    #pragma unroll
    for (int k64=0;k64<4;k64++)
      #pragma unroll
      for (int st=0;st<2;st++){
        f16x8 aw[2], bs[4];
        #pragma unroll
        for (int i=0;i<2;i++) aw[i] = *(const f16x8*)(W1f + ((c*8 + w*2 + i)*4 + k64)*1024 + st*512 + lo);
        #pragma unroll
        for (int j=0;j<4;j++) bs[j] = *(const f16x8*)(Abuf + (k64*4 + j)*1024 + st*512 + lo);
        #pragma unroll
        for (int i=0;i<2;i++)
          #pragma unroll
          for (int j=0;j<4;j++) acc1[i][j] = mfmah(aw[i], bs[j], acc1[i][j]);
      }
    __syncthreads();   // protect Hbuf against FC2(c-1) readers
    // ---- gelu -> Hbuf (A-frag layout, XOR-swizzled) ----
    #pragma unroll
    for (int i=0;i<2;i++){
      int fl = w*32 + i*16 + g*4;      // 0..127
      int kc = fl>>6, kloc = fl&63;
      #pragma unroll
      for (int j=0;j<4;j++){
        int row = j*16 + lr;
        u16x4 hv;
        #pragma unroll
        for (int r=0;r<4;r++){
          float xv = acc1[i][j][r] + b1[c*128 + fl + r];
          hv[r] = f2h(gelu_f(xv));
        }
        int phys = ((kloc>>3) ^ row) & 7;
        *(u16x4*)(Hbuf + row*128 + kc*64 + phys*8 + (kloc&7)) = hv;
      }
    }
    __syncthreads();
    // ---- FC2 partial: k in [c*128,+128); W2 frag-direct; H from LDS ----
    #pragma unroll
    for (int kcl=0;kcl<2;kcl++)
      #pragma unroll
      for (int st=0;st<2;st++){
        f16x8 ah[4], bb[4];
        #pragma unroll
        for (int j=0;j<4;j++) bb[j] = *(const f16x8*)(W2f + ((w*4+j)*16 + c*2 + kcl)*1024 + st*512 + lo);
        #pragma unroll
        for (int i=0;i<4;i++){
          int hrow = i*16 + lr;
          int phys = (((st<<2)|g) ^ hrow) & 7;
          ah[i] = *(const f16x8*)(Hbuf + hrow*128 + kcl*64 + phys*8);
        }
        #pragma unroll
        for (int i=0;i<4;i++)
          #pragma unroll
          for (int j=0;j<4;j++) acc2[i][j] = mfmah(ah[i], bb[j], acc2[i][j]);
      }
  }
  // ---- epilogue: +b2 -> out; LN -> P1 ----
  #pragma unroll
  for (int i=0;i<4;i++)
    #pragma unroll
    for (int j=0;j<4;j++)
      #pragma unroll
      for (int r=0;r<4;r++){
        int row = rowbase + i*16 + g*4 + r;
        int col = w*64 + j*16 + lr;
        acc2[i][j][r] += b2[col];
        out[row*M_ + col] = acc2[i][j][r];
      }
  #pragma unroll
  for (int i=0;i<4;i++)
    #pragma unroll
    for (int r=0;r<4;r++){
      float ps = 0.f, qs = 0.f;
      #pragma unroll
      for (int j=0;j<4;j++){ float t = acc2[i][j][r]; ps += t; qs += t*t; }
      ps += __shfl_xor(ps,1); qs += __shfl_xor(qs,1);
      ps += __shfl_xor(ps,2); qs += __shfl_xor(qs,2);
      ps += __shfl_xor(ps,4); qs += __shfl_xor(qs,4);
      ps += __shfl_xor(ps,8); qs += __shfl_xor(qs,8);
      if (lr == 0){
        int rowl = i*16 + g*4 + r;
        zs[w][rowl][0] = ps;
        zs[w][rowl][1] = qs;
      }
    }
  __syncthreads();
  #pragma unroll
  for (int i=0;i<4;i++)
    #pragma unroll
    for (int r=0;r<4;r++){
      int rowl = i*16 + g*4 + r;
      float sum = zs[0][rowl][0]+zs[1][rowl][0]+zs[2][rowl][0]+zs[3][rowl][0];
      float sq  = zs[0][rowl][1]+zs[1][rowl][1]+zs[2][rowl][1]+zs[3][rowl][1];
      float mean = sum*(1.f/M_);
      float var  = sq*(1.f/M_) - mean*mean;
      float rstd = rsqrtf(var + 1e-5f);
      int row = rowbase + rowl;
      #pragma unroll
      for (int j=0;j<4;j++){
        int col = w*64 + j*16 + lr;
        P1[row*M_ + col] = f2h((acc2[i][j][r]-mean)*rstd*lg[col] + lb[col]);
      }
    }
}

extern "C" void kernel_launch(void* const* d_in, const int* in_sizes, int n_in,
                              void* d_out, int out_size, void* d_ws, size_t ws_size,
                              hipStream_t stream){
  const float* x      = (const float*)d_in[0];
  const float* weight = (const float*)d_in[1];
  const float* wqkv   = (const float*)d_in[2];
  const float* wo     = (const float*)d_in[3];
  const float* ln_g   = (const float*)d_in[4];
  const float* ln_b   = (const float*)d_in[5];
  const float* lnz_g  = (const float*)d_in[6];
  const float* lnz_b  = (const float*)d_in[7];
  const float* fc1_w  = (const float*)d_in[8];
  const float* fc1_b  = (const float*)d_in[9];
  const float* fc2_w  = (const float*)d_in[10];
  const float* fc2_b  = (const float*)d_in[11];
  float* out = (float*)d_out;
  char* ws = (char*)d_ws;
  size_t off = 0;
  u16* wqkvf = (u16*)(ws + off); off += 1572864;   // 4*192*1024 u16
  u16* wof   = (u16*)(ws + off); off += 524288;    // 4*64*1024
  u16* fc1f  = (u16*)(ws + off); off += 524288;    // 256*1024
  u16* fc2f  = (u16*)(ws + off); off += 524288;    // 256*1024
  u16* P1    = (u16*)(ws + off); off += 33554432;  // R*256 f16
  u16* imv   = (u16*)(ws + off); off += 33554432;  // R*256 f16
  // bias(f32 512KB) + weightf(128KB) alias imv head (dead before first k_qkv)
  float* bias   = (float*)imv;
  u16*   weightf = (u16*)((char*)imv + 524288);

  k_bias<<<N_, M_, 0, stream>>>(bias);
  k_pack<<<64, 128, 0, stream>>>(weight, weightf, 256);
  k_pack_qkv<<<768, 128, 0, stream>>>(wqkv, wqkvf);
  k_pack<<<256, 128, 0, stream>>>(wo, wof, 256);      // C=1024 (4 a-blocks of 256), K=256
  k_pack<<<256, 128, 0, stream>>>(fc1_w, fc1f, 256);
  k_pack<<<256, 128, 0, stream>>>(fc2_w, fc2f, 1024); // C=256, K=1024
  k_init<<<R_/128, 512, 0, stream>>>(x, weightf, bias, ln_g, ln_b, out, P1);
  for (int a=0; a<TK_; a++){
    k_qkv<<<dim3(R_/128, 2), 512, 0, stream>>>(P1, wqkvf + a*196608, imv);
    k_scan<<<L_*4, 256, 0, stream>>>(imv, P1);
    k_wo<<<R_/128, 512, 0, stream>>>(P1, wof + a*65536, out, lnz_g, lnz_b);
    k_fc<<<R_/64, 256, 0, stream>>>(P1, fc1f, fc1_b, fc2f, fc2_b, ln_g, ln_b, out);
  }
}

// Round 10
// 860.742 us; speedup vs baseline: 4.9170x; 1.1496x over previous
//
#include <hip/hip_runtime.h>

typedef unsigned int u32;
typedef unsigned short u16;
typedef _Float16 f16;
typedef __attribute__((ext_vector_type(8))) _Float16 f16x8;
typedef __attribute__((ext_vector_type(4))) float f32x4;
typedef __attribute__((ext_vector_type(4))) u16 u16x4;

#define L_ 128
#define N_ 512
#define M_ 256
#define TK_ 4
#define H_ 8
#define R_ (L_*N_)
#define FF_ 1024

__device__ __forceinline__ u16 f2h(float v){ f16 h=(f16)v; return __builtin_bit_cast(u16,h); }
__device__ __forceinline__ float h2f(u16 b){ return (float)__builtin_bit_cast(f16,b); }
__device__ __forceinline__ f32x4 mfmah(f16x8 a, f16x8 b, f32x4 c){
  return __builtin_amdgcn_mfma_f32_16x16x32_f16(a,b,c,0,0,0);
}
// tanh-form gelu
__device__ __forceinline__ float gelu_f(float x){
  float u = x*(0.7978845608f + 0.0356774081f*x*x);
  float e = __expf(u + u);
  float r = __builtin_amdgcn_rcpf(e + 1.f);
  return x - x*r;
}

// Frag-major packing: weight W[C][K], tile (cg,k64):
//   dst[(cg*(K/64)+k64)*1024 + st*512 + g*128 + lr*8 + e] = W[cg*16+lr][k64*64+st*32+g*8+e]
// Wave reads one K=32 frag as 1KB contiguous: base + st*512 + (lane>>4)*128 + (lane&15)*8.

// ---------------- prep ----------------
__global__ void k_bias(float* __restrict__ bias){
  int j = blockIdx.x, l = threadIdx.x;
  int t = l>>1;
  float base = expf(-0.14391156831212757f * (float)t); // ln(10000)/64
  float ang = (float)j * base;
  bias[j*M_ + l] = (l&1) ? cosf(ang) : sinf(ang);
}

// generic f32 [C][K] -> frag-packed f16; grid = (C/16)*(K/64), block 128
__global__ void k_pack(const float* __restrict__ src, u16* __restrict__ dst, int K){
  int b = blockIdx.x; int nk = K>>6; int cg = b/nk, k64 = b%nk;
  int t = threadIdx.x;
  int st = t>>6, g = (t>>4)&3, lr = t&15;
  const float* sp = src + (cg*16+lr)*K + k64*64 + st*32 + g*8;
  f16x8 hv;
  #pragma unroll
  for (int e=0;e<8;e++) hv[e] = (f16)sp[e];
  *(f16x8*)(dst + b*1024 + t*8) = hv;
}

// Wqkv[a,x,hd,d,m] -> frag-packed per a: [grp=hd*6+cidx (48)][k64 (4)][1024]; grid 768, block 128
__global__ void k_pack_qkv(const float* __restrict__ w, u16* __restrict__ dst){
  int b = blockIdx.x;              // a*192 + grp*4 + k64
  int a = b/192; int rmn = b%192; int grp = rmn>>2, k64 = rmn&3;
  int hd = grp/6, cidx = grp%6;
  int t = threadIdx.x;
  int st = t>>6, g = (t>>4)&3, lr = t&15;
  int cl = cidx*16 + lr;           // 0..95
  int x = cl>>5, d = cl&31;
  const float* sp = w + (((a*3+x)*H_+hd)*32 + d)*M_ + k64*64 + st*32 + g*8;
  f16x8 hv;
  #pragma unroll
  for (int e=0;e<8;e++) hv[e] = (f16)sp[e];
  *(f16x8*)(dst + b*1024 + t*8) = hv;
}

// A-staging (f16 src): 64 rows, frag-packed into Abuf[16*1024]. Coalesced 64B/thread.
__device__ __forceinline__ void stageA16(const u16* __restrict__ src, u16* __restrict__ Abuf,
                                         int rowbase, int tid){
  int row = tid>>3, skh = tid&7;
  int k64 = skh>>1, st = skh&1;
  int rg = row>>4, lr = row&15;
  const u16* sp = src + (rowbase+row)*M_ + k64*64 + st*32;
  u16* dp = Abuf + (k64*4+rg)*1024 + st*512 + lr*8;
  #pragma unroll
  for (int gg=0;gg<4;gg++)
    *(uint4*)(dp + gg*128) = *(const uint4*)(sp + gg*8);
}

// ---------------- k_init: z = x @ weight^T + bias; out=z, P1=f16(LN(z)) ----------------
// 64 rows/block, 8 waves (wx = 32-col slice). A frag-packed in LDS; B frag-direct from L2.
__global__ __launch_bounds__(512) void k_init(const float* __restrict__ X, const u16* __restrict__ Wf,
    const float* __restrict__ bias, const float* __restrict__ lg, const float* __restrict__ lb,
    float* __restrict__ out, u16* __restrict__ P1){
  __shared__ __align__(16) u16 Abuf[16*1024];   // 32KB
  __shared__ float zs[8][64][2];
  int tid = threadIdx.x;
  int wx = tid>>6, lane = tid&63;
  int g = lane>>4, lr = lane&15;
  int lo = g*128 + lr*8;
  int rowbase = blockIdx.x*64;
  { // stage A (f32 -> f16 frag-pack), 64B contiguous per thread
    int row = tid>>3, skh = tid&7;
    int k64 = skh>>1, st = skh&1;
    int rg = row>>4, slr = row&15;
    const float* sp = X + (rowbase+row)*M_ + k64*64 + st*32;
    u16* dp = Abuf + (k64*4+rg)*1024 + st*512 + slr*8;
    #pragma unroll
    for (int gg=0;gg<4;gg++){
      f16x8 hv;
      #pragma unroll
      for (int e=0;e<8;e++) hv[e] = (f16)sp[gg*8+e];
      *(f16x8*)(dp + gg*128) = hv;
    }
  }
  __syncthreads();
  f32x4 acc[4][2];
  #pragma unroll
  for (int i=0;i<4;i++){ acc[i][0]=0.f; acc[i][1]=0.f; }
  #pragma unroll
  for (int k64=0;k64<4;k64++)
    #pragma unroll
    for (int st=0;st<2;st++){
      f16x8 a[4], b[2];
      #pragma unroll
      for (int i=0;i<4;i++) a[i] = *(const f16x8*)(Abuf + (k64*4 + i)*1024 + st*512 + lo);
      #pragma unroll
      for (int j=0;j<2;j++) b[j] = *(const f16x8*)(Wf + ((wx*2+j)*4 + k64)*1024 + st*512 + lo);
      #pragma unroll
      for (int i=0;i<4;i++)
        #pragma unroll
        for (int j=0;j<2;j++) acc[i][j] = mfmah(a[i], b[j], acc[i][j]);
    }
  // epilogue: +bias -> out; LN -> P1
  #pragma unroll
  for (int i=0;i<4;i++)
    #pragma unroll
    for (int j=0;j<2;j++)
      #pragma unroll
      for (int r=0;r<4;r++){
        int row = rowbase + i*16 + g*4 + r;
        int col = wx*32 + j*16 + lr;
        acc[i][j][r] += bias[(row & (N_-1))*M_ + col];
        out[row*M_ + col] = acc[i][j][r];
      }
  #pragma unroll
  for (int i=0;i<4;i++)
    #pragma unroll
    for (int r=0;r<4;r++){
      float ps = 0.f, qs = 0.f;
      #pragma unroll
      for (int j=0;j<2;j++){ float t = acc[i][j][r]; ps += t; qs += t*t; }
      ps += __shfl_xor(ps,1); qs += __shfl_xor(qs,1);
      ps += __shfl_xor(ps,2); qs += __shfl_xor(qs,2);
      ps += __shfl_xor(ps,4); qs += __shfl_xor(qs,4);
      ps += __shfl_xor(ps,8); qs += __shfl_xor(qs,8);
      if (lr == 0){
        int rowl = i*16 + g*4 + r;
        zs[wx][rowl][0] = ps;
        zs[wx][rowl][1] = qs;
      }
    }
  __syncthreads();
  #pragma unroll
  for (int i=0;i<4;i++)
    #pragma unroll
    for (int r=0;r<4;r++){
      int rowl = i*16 + g*4 + r;
      float sum=0.f, sq=0.f;
      #pragma unroll
      for (int q=0;q<8;q++){ sum += zs[q][rowl][0]; sq += zs[q][rowl][1]; }
      float mean = sum*(1.f/M_);
      float var  = sq*(1.f/M_) - mean*mean;
      float rstd = rsqrtf(var + 1e-5f);
      int row = rowbase + rowl;
      #pragma unroll
      for (int j=0;j<2;j++){
        int col = wx*32 + j*16 + lr;
        P1[row*M_ + col] = f2h((acc[i][j][r]-mean)*rstd*lg[col] + lb[col]);
      }
    }
}

// ---------------- QKV GEMM + fused rsa -> imv(f16) ----------------
// 64 rows/block, 8 waves = 8 heads. A in LDS; Wqkv frag-direct from L2.
__global__ __launch_bounds__(512) void k_qkv(const u16* __restrict__ P1, const u16* __restrict__ Wq,
    u16* __restrict__ imv){
  __shared__ __align__(16) u16 Abuf[16*1024];   // 32KB
  int tid = threadIdx.x;
  int hd = tid>>6, lane = tid&63;
  int g = lane>>4, lr = lane&15;
  int lo = g*128 + lr*8;
  int rowbase = blockIdx.x*64;
  stageA16(P1, Abuf, rowbase, tid);
  __syncthreads();
  f32x4 acc[4][6];
  #pragma unroll
  for (int i=0;i<4;i++)
    #pragma unroll
    for (int c=0;c<6;c++) acc[i][c] = 0.f;
  const u16* Wb = Wq + hd*6*4096;
  #pragma unroll
  for (int k64=0;k64<4;k64++)
    #pragma unroll
    for (int st=0;st<2;st++){
      f16x8 a[4];
      #pragma unroll
      for (int i=0;i<4;i++) a[i] = *(const f16x8*)(Abuf + (k64*4 + i)*1024 + st*512 + lo);
      #pragma unroll
      for (int c=0;c<6;c++){
        f16x8 b = *(const f16x8*)(Wb + (c*4 + k64)*1024 + st*512 + lo);
        #pragma unroll
        for (int i=0;i<4;i++) acc[i][c] = mfmah(a[i], b, acc[i][c]);
      }
    }
  const float isd = 0.17677669529663687f; // 1/sqrt(32)
  #pragma unroll
  for (int i=0;i<4;i++){
    f32x4 p = acc[i][0]*acc[i][2] + acc[i][1]*acc[i][3];
    #pragma unroll
    for (int r=0;r<4;r++){
      float v = p[r];
      v += __shfl_xor(v,1); v += __shfl_xor(v,2);
      v += __shfl_xor(v,4); v += __shfl_xor(v,8);
      float rsa = v * isd;
      int row = rowbase + i*16 + g*4 + r;
      imv[row*M_ + hd*32 + lr]      = f2h(rsa*acc[i][4][r]);
      imv[row*M_ + hd*32 + 16 + lr] = f2h(rsa*acc[i][5][r]);
    }
  }
}

// ---------------- cumsum over j: hierarchical, grid (L_*4), block (64m x 4jc) ----------------
__global__ __launch_bounds__(256) void k_scan(const u16* __restrict__ imv, u16* __restrict__ P1){
  __shared__ float tot[4][64];
  int bi = blockIdx.x;
  int i = bi>>2, mc = bi&3;
  int tid = threadIdx.x;
  int ml = tid&63, jc = tid>>6;
  int m = mc*64 + ml;
  int base = i*N_*M_ + jc*128*M_ + m;
  float acc = 0.f;
  for (int jb=0;jb<128;jb+=8){
    float t[8];
    #pragma unroll
    for (int u=0;u<8;u++) t[u] = h2f(imv[base + (jb+u)*M_]);
    #pragma unroll
    for (int u=0;u<8;u++) acc += t[u];
  }
  tot[jc][ml] = acc;
  __syncthreads();
  float pre = 0.f;
  #pragma unroll
  for (int q=0;q<3;q++) if (q<jc) pre += tot[q][ml];
  acc = pre;
  for (int jb=0;jb<128;jb+=8){
    float t[8];
    #pragma unroll
    for (int u=0;u<8;u++) t[u] = h2f(imv[base + (jb+u)*M_]);
    #pragma unroll
    for (int u=0;u<8;u++){ acc += t[u]; P1[base + (jb+u)*M_] = f2h(acc); }
  }
}

// ---------------- Wo GEMM + s_old + LN + residual -> P1(f16, in-place) ----------------
__global__ __launch_bounds__(512) void k_wo(u16* __restrict__ P1, const u16* __restrict__ Wf,
    const float* __restrict__ sold, const float* __restrict__ lg, const float* __restrict__ lb){
  __shared__ __align__(16) u16 Abuf[16*1024];   // 32KB
  __shared__ float zs[8][64][2];
  int tid = threadIdx.x;
  int wx = tid>>6, lane = tid&63;
  int g = lane>>4, lr = lane&15;
  int lo = g*128 + lr*8;
  int rowbase = blockIdx.x*64;
  stageA16(P1, Abuf, rowbase, tid);
  __syncthreads();
  f32x4 acc[4][2];
  #pragma unroll
  for (int i=0;i<4;i++){ acc[i][0]=0.f; acc[i][1]=0.f; }
  #pragma unroll
  for (int k64=0;k64<4;k64++)
    #pragma unroll
    for (int st=0;st<2;st++){
      f16x8 a[4], b[2];
      #pragma unroll
      for (int i=0;i<4;i++) a[i] = *(const f16x8*)(Abuf + (k64*4 + i)*1024 + st*512 + lo);
      #pragma unroll
      for (int j=0;j<2;j++) b[j] = *(const f16x8*)(Wf + ((wx*2+j)*4 + k64)*1024 + st*512 + lo);
      #pragma unroll
      for (int i=0;i<4;i++)
        #pragma unroll
        for (int j=0;j<2;j++) acc[i][j] = mfmah(a[i], b[j], acc[i][j]);
    }
  #pragma unroll
  for (int i=0;i<4;i++)
    #pragma unroll
    for (int j=0;j<2;j++)
      #pragma unroll
      for (int r=0;r<4;r++){
        int row = rowbase + i*16 + g*4 + r;
        int col = wx*32 + j*16 + lr;
        acc[i][j][r] += sold[row*M_ + col];
      }
  #pragma unroll
  for (int i=0;i<4;i++)
    #pragma unroll
    for (int r=0;r<4;r++){
      float ps = 0.f, qs = 0.f;
      #pragma unroll
      for (int j=0;j<2;j++){ float t = acc[i][j][r]; ps += t; qs += t*t; }
      ps += __shfl_xor(ps,1); qs += __shfl_xor(qs,1);
      ps += __shfl_xor(ps,2); qs += __shfl_xor(qs,2);
      ps += __shfl_xor(ps,4); qs += __shfl_xor(qs,4);
      ps += __shfl_xor(ps,8); qs += __shfl_xor(qs,8);
      if (lr == 0){
        int rowl = i*16 + g*4 + r;
        zs[wx][rowl][0] = ps;
        zs[wx][rowl][1] = qs;
      }
    }
  __syncthreads();
  #pragma unroll
  for (int i=0;i<4;i++)
    #pragma unroll
    for (int r=0;r<4;r++){
      int rowl = i*16 + g*4 + r;
      float sum=0.f, sq=0.f;
      #pragma unroll
      for (int q=0;q<8;q++){ sum += zs[q][rowl][0]; sq += zs[q][rowl][1]; }
      float mean = sum*(1.f/M_);
      float var  = sq*(1.f/M_) - mean*mean;
      float rstd = rsqrtf(var + 1e-5f);
      int row = rowbase + rowl;
      #pragma unroll
      for (int j=0;j<2;j++){
        int col = wx*32 + j*16 + lr;
        float zv = acc[i][j][r];
        P1[row*M_ + col] = f2h((zv-mean)*rstd*lg[col] + lb[col] + zv);
      }
    }
}

// ---------------- fused MLP + LN: z = gelu(smid@fc1^T+b1)@fc2^T + b2; out=z, P1=f16(LN(z)) ----------------
// 64 rows/block, 8 waves, 8 c-chunks of 128 fcols. A resident; W1/W2 frag-direct from L2.
__global__ __launch_bounds__(512) void k_fc(u16* __restrict__ P1,
    const u16* __restrict__ W1f, const float* __restrict__ b1,
    const u16* __restrict__ W2f, const float* __restrict__ b2,
    const float* __restrict__ lg, const float* __restrict__ lb,
    float* __restrict__ out){
  __shared__ __align__(16) u16 Abuf[16*1024];   // 32KB
  __shared__ __align__(16) u16 Hbuf[64*128];    // 16KB
  __shared__ float zs[8][64][2];                // 4KB
  int tid = threadIdx.x;
  int wx = tid>>6, lane = tid&63;
  int g = lane>>4, lr = lane&15;
  int lo = g*128 + lr*8;
  int rowbase = blockIdx.x*64;
  stageA16(P1, Abuf, rowbase, tid);
  __syncthreads();
  f32x4 acc2[4][2];
  #pragma unroll
  for (int i=0;i<4;i++){ acc2[i][0]=0.f; acc2[i][1]=0.f; }
  for (int c=0;c<8;c++){
    // ---- FC1^T: this wave's 16 fcols = c*128 + wx*16 .. +16; K=256 ----
    f32x4 acc1[4];   // [smidrow frag], C^T: row=fcol, col=smid row
    #pragma unroll
    for (int j=0;j<4;j++) acc1[j] = 0.f;
    #pragma unroll
    for (int k64=0;k64<4;k64++)
      #pragma unroll
      for (int st=0;st<2;st++){
        f16x8 aw = *(const f16x8*)(W1f + ((c*8 + wx)*4 + k64)*1024 + st*512 + lo);
        #pragma unroll
        for (int j=0;j<4;j++){
          f16x8 bs = *(const f16x8*)(Abuf + (k64*4 + j)*1024 + st*512 + lo);
          acc1[j] = mfmah(aw, bs, acc1[j]);
        }
      }
    __syncthreads();   // prior FC2 done reading Hbuf
    // ---- gelu -> Hbuf (A-frag layout, XOR-swizzled) ----
    {
      int fl = wx*16 + g*4;            // fcol local 0..127 (+r)
      int kc = fl>>6, kloc = fl&63;
      float4 b1v = *(const float4*)(b1 + c*128 + fl);
      float bb[4] = {b1v.x, b1v.y, b1v.z, b1v.w};
      #pragma unroll
      for (int j=0;j<4;j++){
        int row = j*16 + lr;
        u16x4 hv;
        #pragma unroll
        for (int r=0;r<4;r++){
          float xv = acc1[j][r] + bb[r];
          hv[r] = f2h(gelu_f(xv));
        }
        int phys = ((kloc>>3) ^ row) & 7;
        *(u16x4*)(Hbuf + row*128 + kc*64 + phys*8 + (kloc&7)) = hv;
      }
    }
    __syncthreads();
    // ---- FC2 partial: k in [c*128,+128); out cols wx*32..+32 ----
    #pragma unroll
    for (int kcl=0;kcl<2;kcl++)
      #pragma unroll
      for (int st=0;st<2;st++){
        f16x8 ah[4], bb2[2];
        #pragma unroll
        for (int j=0;j<2;j++)
          bb2[j] = *(const f16x8*)(W2f + ((wx*2+j)*16 + c*2 + kcl)*1024 + st*512 + lo);
        #pragma unroll
        for (int i=0;i<4;i++){
          int hrow = i*16 + lr;
          int phys = (((st<<2)|g) ^ hrow) & 7;
          ah[i] = *(const f16x8*)(Hbuf + hrow*128 + kcl*64 + phys*8);
        }
        #pragma unroll
        for (int i=0;i<4;i++)
          #pragma unroll
          for (int j=0;j<2;j++) acc2[i][j] = mfmah(ah[i], bb2[j], acc2[i][j]);
      }
  }
  // ---- epilogue: +b2 -> out; LN -> P1 ----
  #pragma unroll
  for (int i=0;i<4;i++)
    #pragma unroll
    for (int j=0;j<2;j++)
      #pragma unroll
      for (int r=0;r<4;r++){
        int row = rowbase + i*16 + g*4 + r;
        int col = wx*32 + j*16 + lr;
        acc2[i][j][r] += b2[col];
        out[row*M_ + col] = acc2[i][j][r];
      }
  #pragma unroll
  for (int i=0;i<4;i++)
    #pragma unroll
    for (int r=0;r<4;r++){
      float ps = 0.f, qs = 0.f;
      #pragma unroll
      for (int j=0;j<2;j++){ float t = acc2[i][j][r]; ps += t; qs += t*t; }
      ps += __shfl_xor(ps,1); qs += __shfl_xor(qs,1);
      ps += __shfl_xor(ps,2); qs += __shfl_xor(qs,2);
      ps += __shfl_xor(ps,4); qs += __shfl_xor(qs,4);
      ps += __shfl_xor(ps,8); qs += __shfl_xor(qs,8);
      if (lr == 0){
        int rowl = i*16 + g*4 + r;
        zs[wx][rowl][0] = ps;
        zs[wx][rowl][1] = qs;
      }
    }
  __syncthreads();
  #pragma unroll
  for (int i=0;i<4;i++)
    #pragma unroll
    for (int r=0;r<4;r++){
      int rowl = i*16 + g*4 + r;
      float sum=0.f, sq=0.f;
      #pragma unroll
      for (int q=0;q<8;q++){ sum += zs[q][rowl][0]; sq += zs[q][rowl][1]; }
      float mean = sum*(1.f/M_);
      float var  = sq*(1.f/M_) - mean*mean;
      float rstd = rsqrtf(var + 1e-5f);
      int row = rowbase + rowl;
      #pragma unroll
      for (int j=0;j<2;j++){
        int col = wx*32 + j*16 + lr;
        P1[row*M_ + col] = f2h((acc2[i][j][r]-mean)*rstd*lg[col] + lb[col]);
      }
    }
}

extern "C" void kernel_launch(void* const* d_in, const int* in_sizes, int n_in,
                              void* d_out, int out_size, void* d_ws, size_t ws_size,
                              hipStream_t stream){
  const float* x      = (const float*)d_in[0];
  const float* weight = (const float*)d_in[1];
  const float* wqkv   = (const float*)d_in[2];
  const float* wo     = (const float*)d_in[3];
  const float* ln_g   = (const float*)d_in[4];
  const float* ln_b   = (const float*)d_in[5];
  const float* lnz_g  = (const float*)d_in[6];
  const float* lnz_b  = (const float*)d_in[7];
  const float* fc1_w  = (const float*)d_in[8];
  const float* fc1_b  = (const float*)d_in[9];
  const float* fc2_w  = (const float*)d_in[10];
  const float* fc2_b  = (const float*)d_in[11];
  float* out = (float*)d_out;
  char* ws = (char*)d_ws;
  size_t off = 0;
  u16* wqkvf = (u16*)(ws + off); off += 1572864;   // 4*192*1024 u16
  u16* wof   = (u16*)(ws + off); off += 524288;    // 256 frags
  u16* fc1f  = (u16*)(ws + off); off += 524288;
  u16* fc2f  = (u16*)(ws + off); off += 524288;
  u16* P1    = (u16*)(ws + off); off += 33554432;  // R*256 f16
  u16* imv   = (u16*)(ws + off); off += 33554432;  // R*256 f16
  // bias(f32 512KB) + weightf(128KB) alias imv head (dead before first k_qkv)
  float* bias   = (float*)imv;
  u16*   weightf = (u16*)((char*)imv + 524288);

  k_bias<<<N_, M_, 0, stream>>>(bias);
  k_pack<<<64, 128, 0, stream>>>(weight, weightf, 256);
  k_pack_qkv<<<768, 128, 0, stream>>>(wqkv, wqkvf);
  k_pack<<<256, 128, 0, stream>>>(wo, wof, 256);      // C=1024 (4 a-blocks), K=256
  k_pack<<<256, 128, 0, stream>>>(fc1_w, fc1f, 256);
  k_pack<<<256, 128, 0, stream>>>(fc2_w, fc2f, 1024); // C=256, K=1024
  k_init<<<R_/64, 512, 0, stream>>>(x, weightf, bias, ln_g, ln_b, out, P1);
  for (int a=0; a<TK_; a++){
    k_qkv<<<R_/64, 512, 0, stream>>>(P1, wqkvf + a*196608, imv);
    k_scan<<<L_*4, 256, 0, stream>>>(imv, P1);
    k_wo<<<R_/64, 512, 0, stream>>>(P1, wof + a*65536, out, lnz_g, lnz_b);
    k_fc<<<R_/64, 512, 0, stream>>>(P1, fc1f, fc1_b, fc2f, fc2_b, ln_g, ln_b, out);
  }
}